// Round 2
// 320.573 us; speedup vs baseline: 1.1009x; 1.1009x over previous
//
#include <hip/hip_runtime.h>
#include <hip/hip_fp16.h>
#include <math.h>

#define SEQ    4096
#define DMODEL 1024

typedef _Float16 half8   __attribute__((ext_vector_type(8)));
typedef _Float16 half4v  __attribute__((ext_vector_type(4)));
typedef float    floatx4 __attribute__((ext_vector_type(4)));

__device__ inline void split_val(float v, _Float16& h, _Float16& l) {
    _Float16 hh = (_Float16)v;
    h = hh;
    l = (_Float16)(v - (float)hh);
}

// ---------------------------------------------------------------------------
// Fused prep: blocks 0..3071 transpose wq/wk/wv (32x32 tiles); blocks
// 3072..4095 split x into hi/lo fp16 (4 float4 per thread = full x).
// ---------------------------------------------------------------------------
__global__ __launch_bounds__(256) void prep(const float* __restrict__ x,
                                            const float* __restrict__ wq,
                                            const float* __restrict__ wk,
                                            const float* __restrict__ wv,
                                            _Float16* __restrict__ x_hi,
                                            _Float16* __restrict__ x_lo,
                                            _Float16* __restrict__ wqkT_hi,
                                            _Float16* __restrict__ wqkT_lo,
                                            _Float16* __restrict__ wvT) {
    __shared__ float tile[32][33];
    const int b = blockIdx.x;
    if (b < 3072) {
        const int which = b >> 10;           // 0=wq 1=wk 2=wv
        const int bb = b & 1023;
        const int c0 = (bb & 31) * 32;
        const int r0 = (bb >> 5) * 32;
        const float* w = (which == 0) ? wq : (which == 1) ? wk : wv;
        const int tx = threadIdx.x & 31, ty = threadIdx.x >> 5;
#pragma unroll
        for (int j = 0; j < 4; ++j)
            tile[ty * 4 + j][tx] = w[(size_t)(r0 + ty * 4 + j) * DMODEL + c0 + tx];
        __syncthreads();
        if (which < 2) {
            _Float16* th = wqkT_hi + (size_t)which * DMODEL * DMODEL;
            _Float16* tl = wqkT_lo + (size_t)which * DMODEL * DMODEL;
#pragma unroll
            for (int j = 0; j < 4; ++j) {
                float v = tile[tx][ty * 4 + j];
                size_t idx = (size_t)(c0 + ty * 4 + j) * DMODEL + r0 + tx;
                _Float16 h, l;
                split_val(v, h, l);
                th[idx] = h;
                tl[idx] = l;
            }
        } else {
#pragma unroll
            for (int j = 0; j < 4; ++j)
                wvT[(size_t)(c0 + ty * 4 + j) * DMODEL + r0 + tx] =
                    (_Float16)tile[tx][ty * 4 + j];
        }
    } else {
        const int t0 = (b - 3072) * 256 + threadIdx.x;
#pragma unroll
        for (int rep = 0; rep < 4; ++rep) {
            const size_t i = (size_t)t0 + (size_t)rep * 262144;
            floatx4 v = *(const floatx4*)(x + 4 * i);
            half4v h, l;
#pragma unroll
            for (int j = 0; j < 4; ++j) {
                _Float16 hh = (_Float16)v[j];
                _Float16 ll = (_Float16)(v[j] - (float)hh);
                h[j] = hh;
                l[j] = ll;
            }
            *(half4v*)(x_hi + 4 * i) = h;
            *(half4v*)(x_lo + 4 * i) = l;
        }
    }
}

// ---------------------------------------------------------------------------
// QK projection: 3-product split fp16 GEMM (16x16x32), tile 128x128, BK=32.
// C = (x_hi+x_lo) @ (wqk_hi+wqk_lo)^T.
// Epilogue writes concatenated hi/lo layout Qcat/Kcat [4096][2048]
// (hi in cols [0,1024), lo in cols [1024,2048)) so the score GEMM becomes a
// plain K=2048 fp16 GEMM (exact 4-product (hi+lo)x(hi+lo)).
// ---------------------------------------------------------------------------
__global__ __launch_bounds__(256) void gemm_qkproj(
    const _Float16* __restrict__ Ahi, const _Float16* __restrict__ Alo,
    const _Float16* __restrict__ Bhi, const _Float16* __restrict__ Blo,
    _Float16* __restrict__ Qcat, _Float16* __restrict__ Kcat) {
    __shared__ _Float16 Ah[128][32];
    __shared__ _Float16 Al[128][32];
    __shared__ _Float16 Bh[128][32];
    __shared__ _Float16 Bl[128][32];

    const int tid = threadIdx.x;
    const int lane = tid & 63;
    const int w = tid >> 6;
    const int wm = (w >> 1) * 64;
    const int wn = (w & 1) * 64;

    const int rowA0 = blockIdx.y * 128;
    const int colB0 = blockIdx.x * 128;

    const int sr = lane >> 2;
    const int sc = lane & 3;
    const int r0 = w * 32 + sr;
    const int r1 = r0 + 16;
    const int cg0 = sc ^ ((r0 >> 1) & 3);
    const int cg1 = sc ^ ((r1 >> 1) & 3);

    const char* gp[8];
    gp[0] = (const char*)(Ahi + (size_t)(rowA0 + r0) * DMODEL) + cg0 * 16;
    gp[1] = (const char*)(Ahi + (size_t)(rowA0 + r1) * DMODEL) + cg1 * 16;
    gp[2] = (const char*)(Alo + (size_t)(rowA0 + r0) * DMODEL) + cg0 * 16;
    gp[3] = (const char*)(Alo + (size_t)(rowA0 + r1) * DMODEL) + cg1 * 16;
    gp[4] = (const char*)(Bhi + (size_t)(colB0 + r0) * DMODEL) + cg0 * 16;
    gp[5] = (const char*)(Bhi + (size_t)(colB0 + r1) * DMODEL) + cg1 * 16;
    gp[6] = (const char*)(Blo + (size_t)(colB0 + r0) * DMODEL) + cg0 * 16;
    gp[7] = (const char*)(Blo + (size_t)(colB0 + r1) * DMODEL) + cg1 * 16;

    _Float16* lp[8] = {
        &Ah[w * 32][0], &Ah[w * 32 + 16][0],
        &Al[w * 32][0], &Al[w * 32 + 16][0],
        &Bh[w * 32][0], &Bh[w * 32 + 16][0],
        &Bl[w * 32][0], &Bl[w * 32 + 16][0],
    };

    const int fm = lane & 15;
    const int fq = lane >> 4;
    const int ck = ((fq ^ ((fm >> 1) & 3)) * 8);

    floatx4 acc[4][4] = {};

    for (int k0 = 0; k0 < DMODEL; k0 += 32) {
#pragma unroll
        for (int t = 0; t < 8; ++t)
            __builtin_amdgcn_global_load_lds(
                (const __attribute__((address_space(1))) void*)gp[t],
                (__attribute__((address_space(3))) void*)lp[t], 16, 0, 0);
#pragma unroll
        for (int t = 0; t < 8; ++t) gp[t] += 64;
        __syncthreads();

        half8 ahv[4], bhv[4], blv[4], alv[4];
#pragma unroll
        for (int i = 0; i < 4; ++i) {
            ahv[i] = *(const half8*)&Ah[wm + i * 16 + fm][ck];
            bhv[i] = *(const half8*)&Bh[wn + i * 16 + fm][ck];
        }
#pragma unroll
        for (int i = 0; i < 4; ++i)
#pragma unroll
            for (int j = 0; j < 4; ++j)
                acc[i][j] = __builtin_amdgcn_mfma_f32_16x16x32_f16(ahv[i], bhv[j], acc[i][j], 0, 0, 0);
#pragma unroll
        for (int i = 0; i < 4; ++i) blv[i] = *(const half8*)&Bl[wn + i * 16 + fm][ck];
#pragma unroll
        for (int i = 0; i < 4; ++i)
#pragma unroll
            for (int j = 0; j < 4; ++j)
                acc[i][j] = __builtin_amdgcn_mfma_f32_16x16x32_f16(ahv[i], blv[j], acc[i][j], 0, 0, 0);
#pragma unroll
        for (int i = 0; i < 4; ++i) alv[i] = *(const half8*)&Al[wm + i * 16 + fm][ck];
#pragma unroll
        for (int i = 0; i < 4; ++i)
#pragma unroll
            for (int j = 0; j < 4; ++j)
                acc[i][j] = __builtin_amdgcn_mfma_f32_16x16x32_f16(alv[i], bhv[j], acc[i][j], 0, 0, 0);
        __syncthreads();
    }

    _Float16* dcat = Qcat;
    int cbase = colB0;
    if (colB0 >= 1024) { dcat = Kcat; cbase = colB0 - 1024; }

#pragma unroll
    for (int i = 0; i < 4; ++i) {
        const int growb = rowA0 + wm + i * 16 + fq * 4;
#pragma unroll
        for (int j = 0; j < 4; ++j) {
            const int gcol = wn + j * 16 + fm;
#pragma unroll
            for (int r = 0; r < 4; ++r) {
                float v = acc[i][j][r];
                size_t idx = (size_t)(growb + r) * 2048 + cbase + gcol;
                _Float16 h, l;
                split_val(v, h, l);
                dcat[idx] = h;           // hi half
                dcat[idx + 1024] = l;    // lo half
            }
        }
    }
}

// ---------------------------------------------------------------------------
// Score GEMM, deep-pipelined: S = Qcat @ Kcat^T (plain fp16, K=2048 = exact
// (Qhi+Qlo)(Khi+Klo) 4-product), tile 256x256, BK=32, 8 waves (2M x 4N),
// per-wave output 128x64 (8x4 16x16x32 frags).
//
// Pipeline: 4-slot circular LDS ring (4 x (A 16KB + B 16KB) = 128KB),
// prefetch distance 3 K-tiles via global_load_lds, counted vmcnt gate
// (vmcnt(8): tiles t+2,t+3 = 8 vmem instrs stay in flight across barriers;
// never vmcnt(0) until the drain tail). Race ledger: STAGE for tile tau
// issues during tile tau-3 and writes slot tau&3 = (tau-4)&3's successor;
// a write into slot (t+3)&3 aliases only tile t-1, whose ds_reads completed
// (register dependency before that tile's MFMAs) ahead of the gate barrier
// entering tile t. Gate vmcnt(8) at end of tile t guarantees tile t+1's
// loads have landed while t+2/t+3 stay outstanding.
//
// LDS bank swizzle (both-sides, rule #21): LDS dest is linear (HW writes
// wavebase + lane*16); the global SOURCE k-granule is pre-swizzled
// pgs = pg ^ ((pr>>1)&3), and reads use ck = (fq ^ ((fm>>1)&3))*8. This is
// the proven conflict-free pattern from the 128-tile kernels
// (SQ_LDS_BANK_CONFLICT = 0). Base rows are multiples of 16 so (row>>1)&3
// reduces to (fm>>1)&3 on the read side and is invariant under +128 on the
// staging side.
//
// Epilogue: per-wave 64-col tile-softmax: m_t = span max, P = exp(s-m_t),
// (m_t, sum) -> Marr/Larr at tprime = (colB0+wn)/64.
// ---------------------------------------------------------------------------
__global__ __launch_bounds__(512, 2) void gemm_score_dp(
    const _Float16* __restrict__ Qc,   // [4096][2048]
    const _Float16* __restrict__ Kc,   // [4096][2048]
    _Float16* __restrict__ Ph, float* __restrict__ Marr, float* __restrict__ Larr,
    float scale) {
    __shared__ _Float16 As[4][256][32];   // 64 KB
    __shared__ _Float16 Bs[4][256][32];   // 64 KB

    const int tid  = threadIdx.x;
    const int lane = tid & 63;
    const int wid  = tid >> 6;
    const int wm   = (wid >> 2) * 128;    // 0 or 128
    const int wn   = (wid & 3) * 64;      // 0,64,128,192

    const int rowA0 = blockIdx.y * 256;
    const int colB0 = blockIdx.x * 256;

    // Staging: thread tid owns LDS granules tid and tid+512 (byte tid*16 —
    // matches the HW's wavebase+lane*16 write pattern). Global source
    // k-granule is pre-swizzled so that swizzled reads see linear data.
    const int pr  = tid >> 2;
    const int pg  = tid & 3;
    const int pgs = pg ^ ((pr >> 1) & 3);

    const char* aSrc0 = (const char*)(Qc + (size_t)(rowA0 + pr) * 2048) + pgs * 16;
    const char* aSrc1 = (const char*)(Qc + (size_t)(rowA0 + pr + 128) * 2048) + pgs * 16;
    const char* bSrc0 = (const char*)(Kc + (size_t)(colB0 + pr) * 2048) + pgs * 16;
    const char* bSrc1 = (const char*)(Kc + (size_t)(colB0 + pr + 128) * 2048) + pgs * 16;

#define STAGE_A(t)                                                                  \
    do {                                                                            \
        const int _s = (t) & 3;                                                     \
        const size_t _ko = (size_t)(t) * 64;  /* 32 halves = 64 bytes */            \
        __builtin_amdgcn_global_load_lds(                                           \
            (const __attribute__((address_space(1))) void*)(aSrc0 + _ko),           \
            (__attribute__((address_space(3))) void*)&As[_s][pr][pg * 8], 16, 0, 0);\
        __builtin_amdgcn_global_load_lds(                                           \
            (const __attribute__((address_space(1))) void*)(aSrc1 + _ko),           \
            (__attribute__((address_space(3))) void*)&As[_s][pr + 128][pg * 8], 16, 0, 0);\
    } while (0)

#define STAGE_B(t)                                                                  \
    do {                                                                            \
        const int _s = (t) & 3;                                                     \
        const size_t _ko = (size_t)(t) * 64;                                        \
        __builtin_amdgcn_global_load_lds(                                           \
            (const __attribute__((address_space(1))) void*)(bSrc0 + _ko),           \
            (__attribute__((address_space(3))) void*)&Bs[_s][pr][pg * 8], 16, 0, 0);\
        __builtin_amdgcn_global_load_lds(                                           \
            (const __attribute__((address_space(1))) void*)(bSrc1 + _ko),           \
            (__attribute__((address_space(3))) void*)&Bs[_s][pr + 128][pg * 8], 16, 0, 0);\
    } while (0)

    const int fm = lane & 15;
    const int fq = lane >> 4;
    const int ck = (fq ^ ((fm >> 1) & 3)) * 8;

    floatx4 acc[8][4] = {};

    auto tile_body = [&](int t, bool do_stage) {
        const int s = t & 3;
        // ---- phase A: rows [wm, wm+64) x all 4 j ----
        half8 av[4], bv[4];
#pragma unroll
        for (int i = 0; i < 4; ++i) av[i] = *(const half8*)&As[s][wm + i * 16 + fm][ck];
#pragma unroll
        for (int j = 0; j < 4; ++j) bv[j] = *(const half8*)&Bs[s][wn + j * 16 + fm][ck];
        if (do_stage) STAGE_A(t + 3);
        asm volatile("" ::: "memory");
        __builtin_amdgcn_s_barrier();
        asm volatile("" ::: "memory");
        __builtin_amdgcn_s_setprio(1);
#pragma unroll
        for (int i = 0; i < 4; ++i)
#pragma unroll
            for (int j = 0; j < 4; ++j)
                acc[i][j] = __builtin_amdgcn_mfma_f32_16x16x32_f16(av[i], bv[j], acc[i][j], 0, 0, 0);
        __builtin_amdgcn_s_setprio(0);
        asm volatile("" ::: "memory");
        __builtin_amdgcn_s_barrier();
        asm volatile("" ::: "memory");
        // ---- phase B: rows [wm+64, wm+128) x all 4 j (bv reused) ----
        half8 av2[4];
#pragma unroll
        for (int i = 0; i < 4; ++i) av2[i] = *(const half8*)&As[s][wm + 64 + i * 16 + fm][ck];
        if (do_stage) STAGE_B(t + 3);
        asm volatile("" ::: "memory");
        __builtin_amdgcn_s_barrier();
        asm volatile("" ::: "memory");
        __builtin_amdgcn_s_setprio(1);
#pragma unroll
        for (int i = 0; i < 4; ++i)
#pragma unroll
            for (int j = 0; j < 4; ++j)
                acc[i + 4][j] = __builtin_amdgcn_mfma_f32_16x16x32_f16(av2[i], bv[j], acc[i + 4][j], 0, 0, 0);
        __builtin_amdgcn_s_setprio(0);
    };

    // Prologue: stage tiles 0,1,2 (12 vmem instrs/wave); gate on tile 0
    // (allow tiles 1,2 = 8 instrs outstanding).
    STAGE_A(0); STAGE_B(0);
    STAGE_A(1); STAGE_B(1);
    STAGE_A(2); STAGE_B(2);
    asm volatile("s_waitcnt vmcnt(8)" ::: "memory");
    __builtin_amdgcn_s_barrier();
    asm volatile("" ::: "memory");

    // Main loop: tiles 0..60 stage tile t+3 and gate at vmcnt(8).
#pragma unroll 1
    for (int t = 0; t < 61; ++t) {
        tile_body(t, true);
        asm volatile("s_waitcnt vmcnt(8)" ::: "memory");
        __builtin_amdgcn_s_barrier();
        asm volatile("" ::: "memory");
    }
    // Drain tail: tiles 61 (wait 62 done), 62 (wait 63 done), 63.
    tile_body(61, false);
    asm volatile("s_waitcnt vmcnt(4)" ::: "memory");
    __builtin_amdgcn_s_barrier();
    asm volatile("" ::: "memory");
    tile_body(62, false);
    asm volatile("s_waitcnt vmcnt(0)" ::: "memory");
    __builtin_amdgcn_s_barrier();
    asm volatile("" ::: "memory");
    tile_body(63, false);
#undef STAGE_A
#undef STAGE_B

    // ---- tile-softmax epilogue over this wave's 128x64 span ----
    const int tprime = (colB0 + wn) >> 6;
#pragma unroll
    for (int i = 0; i < 8; ++i) {
#pragma unroll
        for (int r = 0; r < 4; ++r) {
            const int grow = rowA0 + wm + i * 16 + fq * 4 + r;
            float s0 = acc[i][0][r] * scale;
            float s1 = acc[i][1][r] * scale;
            float s2 = acc[i][2][r] * scale;
            float s3 = acc[i][3][r] * scale;
            float mx = fmaxf(fmaxf(s0, s1), fmaxf(s2, s3));
            mx = fmaxf(mx, __shfl_xor(mx, 1));
            mx = fmaxf(mx, __shfl_xor(mx, 2));
            mx = fmaxf(mx, __shfl_xor(mx, 4));
            mx = fmaxf(mx, __shfl_xor(mx, 8));
            float p0 = __expf(s0 - mx);
            float p1 = __expf(s1 - mx);
            float p2 = __expf(s2 - mx);
            float p3 = __expf(s3 - mx);
            float sum = p0 + p1 + p2 + p3;
            sum += __shfl_xor(sum, 1);
            sum += __shfl_xor(sum, 2);
            sum += __shfl_xor(sum, 4);
            sum += __shfl_xor(sum, 8);
            _Float16* prow = Ph + (size_t)grow * SEQ + colB0 + wn + fm;
            prow[0]  = (_Float16)p0;
            prow[16] = (_Float16)p1;
            prow[32] = (_Float16)p2;
            prow[48] = (_Float16)p3;
            if (fm == 0) {
                Marr[(size_t)grow * 64 + tprime] = mx;
                Larr[(size_t)grow * 64 + tprime] = sum;
            }
        }
    }
}

// ---------------------------------------------------------------------------
// Per-row finalize: wave 0 computes m*, L, c_t = e^(m_t-m*)/L into LDS;
// all 256 threads rescale the row's 4096 fp16 P values in place.
// ---------------------------------------------------------------------------
__global__ __launch_bounds__(256) void reduce_scale(const float* __restrict__ Marr,
                                                    const float* __restrict__ Larr,
                                                    _Float16* __restrict__ P) {
    __shared__ float c_tab[64];
    const int tid = threadIdx.x;
    const int row = blockIdx.x;

    if (tid < 64) {
        float mt = Marr[(size_t)row * 64 + tid];
        float lt = Larr[(size_t)row * 64 + tid];
        float m = mt;
#pragma unroll
        for (int off = 32; off > 0; off >>= 1) m = fmaxf(m, __shfl_xor(m, off));
        float contrib = lt * __expf(mt - m);
        float L = contrib;
#pragma unroll
        for (int off = 32; off > 0; off >>= 1) L += __shfl_xor(L, off);
        c_tab[tid] = __expf(mt - m) / L;
    }
    __syncthreads();

    _Float16* prow = P + (size_t)row * SEQ;
#pragma unroll
    for (int i = 0; i < 4; ++i) {
        const int col = i * 1024 + (tid << 2);
        const _Float16 c = (_Float16)c_tab[col >> 6];
        half4v v = *(const half4v*)(prow + col);
        v[0] *= c; v[1] *= c; v[2] *= c; v[3] *= c;
        *(half4v*)(prow + col) = v;
    }
}

// ---------------------------------------------------------------------------
// Plain fp16 MFMA GEMM, tile 128x64 (16x16x32): V-projection and PV.
// OUT_HALF==0: fp32 out. OUT_HALF==1: fp16 out.
// ---------------------------------------------------------------------------
template <int OUT_HALF>
__global__ __launch_bounds__(256) void gemm_h16_n64(
    const _Float16* __restrict__ A, int lda,
    const _Float16* __restrict__ B, int ldb,
    float* __restrict__ Cf, _Float16* __restrict__ Ch,
    int N, int K) {
    __shared__ _Float16 Ah[128][32];
    __shared__ _Float16 Bh[64][32];

    const int tid = threadIdx.x;
    const int lane = tid & 63;
    const int w = tid >> 6;
    const int wm = (w >> 1) * 64;
    const int wn = (w & 1) * 32;

    const int rowA0 = blockIdx.y * 128;
    const int colB0 = blockIdx.x * 64;

    const int sr = lane >> 2;
    const int sc = lane & 3;
    const int ra0 = w * 32 + sr;
    const int ra1 = ra0 + 16;
    const int rb0 = w * 16 + sr;
    const int cga0 = sc ^ ((ra0 >> 1) & 3);
    const int cga1 = sc ^ ((ra1 >> 1) & 3);
    const int cgb0 = sc ^ ((rb0 >> 1) & 3);

    const char* gp[3];
    gp[0] = (const char*)(A + (size_t)(rowA0 + ra0) * lda) + cga0 * 16;
    gp[1] = (const char*)(A + (size_t)(rowA0 + ra1) * lda) + cga1 * 16;
    gp[2] = (const char*)(B + (size_t)(colB0 + rb0) * ldb) + cgb0 * 16;

    _Float16* lp[3] = {
        &Ah[w * 32][0], &Ah[w * 32 + 16][0],
        &Bh[w * 16][0],
    };

    const int fm = lane & 15;
    const int fq = lane >> 4;
    const int ck = ((fq ^ ((fm >> 1) & 3)) * 8);

    floatx4 acc[4][2] = {};

    for (int k0 = 0; k0 < K; k0 += 32) {
#pragma unroll
        for (int t = 0; t < 3; ++t)
            __builtin_amdgcn_global_load_lds(
                (const __attribute__((address_space(1))) void*)gp[t],
                (__attribute__((address_space(3))) void*)lp[t], 16, 0, 0);
#pragma unroll
        for (int t = 0; t < 3; ++t) gp[t] += 64;
        __syncthreads();

        half8 av[4], bv[2];
#pragma unroll
        for (int i = 0; i < 4; ++i)
            av[i] = *(const half8*)&Ah[wm + i * 16 + fm][ck];
#pragma unroll
        for (int j = 0; j < 2; ++j)
            bv[j] = *(const half8*)&Bh[wn + j * 16 + fm][ck];
#pragma unroll
        for (int i = 0; i < 4; ++i)
#pragma unroll
            for (int j = 0; j < 2; ++j)
                acc[i][j] = __builtin_amdgcn_mfma_f32_16x16x32_f16(av[i], bv[j], acc[i][j], 0, 0, 0);
        __syncthreads();
    }

#pragma unroll
    for (int i = 0; i < 4; ++i) {
        const int growb = rowA0 + wm + i * 16 + fq * 4;
#pragma unroll
        for (int j = 0; j < 2; ++j) {
            const int gcol = colB0 + wn + j * 16 + fm;
#pragma unroll
            for (int r = 0; r < 4; ++r) {
                float v = acc[i][j][r];
                size_t idx = (size_t)(growb + r) * N + gcol;
                if (OUT_HALF) Ch[idx] = (_Float16)v;
                else          Cf[idx] = v;
            }
        }
    }
}

// ---------------------------------------------------------------------------
// Workspace layout (104 MB used):
//  [0,32M)   P fp16 [4096][4096] (region reused: x_hi [0,8M), x_lo [8,16M),
//            wqkT_hi [16,20M), wqkT_lo [20,24M), wvT [24,26M) all dead
//            before the score kernel writes P)
//  [32,33M)  Marr fp32 [4096][64]   [33,34M) Larr fp32 [4096][64]
//  [64,80M)  Qcat fp16 [4096][2048] (hi cols 0..1023, lo cols 1024..2047)
//  [80,96M)  Kcat fp16 [4096][2048]
//  [96,104M) VT fp16 [1024][4096]
// ---------------------------------------------------------------------------
extern "C" void kernel_launch(void* const* d_in, const int* in_sizes, int n_in,
                              void* d_out, int out_size, void* d_ws, size_t ws_size,
                              hipStream_t stream) {
    const float* x  = (const float*)d_in[0];
    const float* wq = (const float*)d_in[1];
    const float* wk = (const float*)d_in[2];
    const float* wv = (const float*)d_in[3];
    float* out = (float*)d_out;

    char* base = (char*)d_ws;
    const size_t MB = 1u << 20;
    _Float16* P       = (_Float16*)base;               // [4096][4096]
    _Float16* x_hi    = (_Float16*)(base + 0 * MB);
    _Float16* x_lo    = (_Float16*)(base + 8 * MB);
    _Float16* wqkT_hi = (_Float16*)(base + 16 * MB);   // [2048][1024]
    _Float16* wqkT_lo = (_Float16*)(base + 20 * MB);
    _Float16* wvT     = (_Float16*)(base + 24 * MB);   // [1024][1024]
    float*    Marr    = (float*)(base + 32 * MB);
    float*    Larr    = (float*)(base + 33 * MB);
    _Float16* Qcat    = (_Float16*)(base + 64 * MB);   // [4096][2048]
    _Float16* Kcat    = (_Float16*)(base + 80 * MB);   // [4096][2048]
    _Float16* VT      = (_Float16*)(base + 96 * MB);   // [1024][4096]

    // 1) fused prep
    prep<<<4096, 256, 0, stream>>>(x, wq, wk, wv, x_hi, x_lo, wqkT_hi, wqkT_lo, wvT);

    // 2) QK projection (concat hi/lo outputs, ldc=2048)
    dim3 gqk(2048 / 128, SEQ / 128);   // (16,32)
    gemm_qkproj<<<gqk, 256, 0, stream>>>(x_hi, x_lo, wqkT_hi, wqkT_lo, Qcat, Kcat);
    // V^T = wv^T @ x^T, plain fp16, tile 128x64
    dim3 gvt(SEQ / 64, DMODEL / 128);  // (64,8)
    gemm_h16_n64<1><<<gvt, 256, 0, stream>>>(wvT, DMODEL, x_hi, DMODEL,
                                             nullptr, VT, SEQ, DMODEL);

    // 3) scores + tile-softmax, deep-pipelined 256x256 K=2048 plain fp16
    dim3 gs(SEQ / 256, SEQ / 256);     // (16,16)
    gemm_score_dp<<<gs, dim3(512), 0, stream>>>(Qcat, Kcat, P, Marr, Larr,
                                                1.0f / 32.0f);

    // 4) finalize: P *= c_t(row)  (in place, exact softmax)
    reduce_scale<<<SEQ, 256, 0, stream>>>(Marr, Larr, P);

    // 5) out = P @ V, plain fp16
    gemm_h16_n64<0><<<dim3(DMODEL / 64, SEQ / 128), 256, 0, stream>>>(
        P, SEQ, VT, SEQ, out, nullptr, DMODEL, SEQ);
}

// Round 3
// 303.184 us; speedup vs baseline: 1.1640x; 1.0574x over previous
//
#include <hip/hip_runtime.h>
#include <hip/hip_fp16.h>
#include <math.h>

#define SEQ    4096
#define DMODEL 1024

typedef _Float16 half8   __attribute__((ext_vector_type(8)));
typedef _Float16 half4v  __attribute__((ext_vector_type(4)));
typedef float    floatx4 __attribute__((ext_vector_type(4)));

__device__ inline void split_val(float v, _Float16& h, _Float16& l) {
    _Float16 hh = (_Float16)v;
    h = hh;
    l = (_Float16)(v - (float)hh);
}

// ---------------------------------------------------------------------------
// Fused prep: blocks 0..3071 transpose wq/wk/wv (32x32 tiles); blocks
// 3072..4095 split x into hi/lo fp16 (4 float4 per thread = full x).
// ---------------------------------------------------------------------------
__global__ __launch_bounds__(256) void prep(const float* __restrict__ x,
                                            const float* __restrict__ wq,
                                            const float* __restrict__ wk,
                                            const float* __restrict__ wv,
                                            _Float16* __restrict__ x_hi,
                                            _Float16* __restrict__ x_lo,
                                            _Float16* __restrict__ wqkT_hi,
                                            _Float16* __restrict__ wqkT_lo,
                                            _Float16* __restrict__ wvT) {
    __shared__ float tile[32][33];
    const int b = blockIdx.x;
    if (b < 3072) {
        const int which = b >> 10;           // 0=wq 1=wk 2=wv
        const int bb = b & 1023;
        const int c0 = (bb & 31) * 32;
        const int r0 = (bb >> 5) * 32;
        const float* w = (which == 0) ? wq : (which == 1) ? wk : wv;
        const int tx = threadIdx.x & 31, ty = threadIdx.x >> 5;
#pragma unroll
        for (int j = 0; j < 4; ++j)
            tile[ty * 4 + j][tx] = w[(size_t)(r0 + ty * 4 + j) * DMODEL + c0 + tx];
        __syncthreads();
        if (which < 2) {
            _Float16* th = wqkT_hi + (size_t)which * DMODEL * DMODEL;
            _Float16* tl = wqkT_lo + (size_t)which * DMODEL * DMODEL;
#pragma unroll
            for (int j = 0; j < 4; ++j) {
                float v = tile[tx][ty * 4 + j];
                size_t idx = (size_t)(c0 + ty * 4 + j) * DMODEL + r0 + tx;
                _Float16 h, l;
                split_val(v, h, l);
                th[idx] = h;
                tl[idx] = l;
            }
        } else {
#pragma unroll
            for (int j = 0; j < 4; ++j)
                wvT[(size_t)(c0 + ty * 4 + j) * DMODEL + r0 + tx] =
                    (_Float16)tile[tx][ty * 4 + j];
        }
    } else {
        const int t0 = (b - 3072) * 256 + threadIdx.x;
#pragma unroll
        for (int rep = 0; rep < 4; ++rep) {
            const size_t i = (size_t)t0 + (size_t)rep * 262144;
            floatx4 v = *(const floatx4*)(x + 4 * i);
            half4v h, l;
#pragma unroll
            for (int j = 0; j < 4; ++j) {
                _Float16 hh = (_Float16)v[j];
                _Float16 ll = (_Float16)(v[j] - (float)hh);
                h[j] = hh;
                l[j] = ll;
            }
            *(half4v*)(x_hi + 4 * i) = h;
            *(half4v*)(x_lo + 4 * i) = l;
        }
    }
}

// ---------------------------------------------------------------------------
// QK projection, deep-pipelined: exact 3-product split GEMM expressed as ONE
// pipelined fp16 GEMM over a virtual K=3072: segment 0 (t=0..31) x_hi·w_hi,
// segment 1 (t=32..63) x_hi·w_lo, segment 2 (t=64..95) x_lo·w_hi — per-tile
// operand-base select, identical math to the old 3-pass kernel.
// Tile 128(M)x256(N), BK=32, 8 waves (2Mx4N), per-wave 64x64 (acc[4][4]).
// 4-slot LDS ring (A 8KB + B 16KB per slot = 96KB), 3 vmem instrs per tile
// (A=1, B=2), counted gate vmcnt(6) (2 tiles in flight across barriers).
// LDS swizzle: linear dest, pre-swizzled global source granule
// pgs = pg ^ ((row>>1)&3), reads at ck = (fq ^ ((fm>>1)&3))*8 (proven
// conflict-free pair for [*][32] rows).
// Epilogue: split_val -> Qcat/Kcat [4096][2048] (hi cols 0..1023, lo +1024).
// ---------------------------------------------------------------------------
__global__ __launch_bounds__(512, 1) void gemm_qkproj_dp(
    const _Float16* __restrict__ Ahi, const _Float16* __restrict__ Alo,   // x_hi/x_lo [4096][1024]
    const _Float16* __restrict__ Bhi, const _Float16* __restrict__ Blo,   // wqkT_hi/lo [2048][1024]
    _Float16* __restrict__ Qcat, _Float16* __restrict__ Kcat) {
    __shared__ _Float16 As[4][128][32];   // 32 KB
    __shared__ _Float16 Bs[4][256][32];   // 64 KB

    const int tid  = threadIdx.x;
    const int lane = tid & 63;
    const int wid  = tid >> 6;
    const int wm   = (wid >> 2) * 64;     // 0,64
    const int wn   = (wid & 3) * 64;      // 0,64,128,192

    // XCD-aware bijective swizzle: nwg = 256 (grid 8 x 32), 256 = 8*32.
    const int lin = blockIdx.y * 8 + blockIdx.x;
    const int swz = (lin & 7) * 32 + (lin >> 3);
    const int rowA0 = (swz >> 3) * 128;
    const int colB0 = (swz & 7) * 256;

    // A staging: 512 granules (128 rows x 4), 1 per thread.
    const int ar  = tid >> 2;
    const int ag  = tid & 3;
    const int ags = ag ^ ((ar >> 1) & 3);
    const char* aHiB = (const char*)(Ahi + (size_t)(rowA0 + ar) * DMODEL) + ags * 16;
    const char* aLoB = (const char*)(Alo + (size_t)(rowA0 + ar) * DMODEL) + ags * 16;
    // B staging: 1024 granules (256 rows x 4), 2 per thread (rows r, r+128).
    const int br  = tid >> 2;
    const int bg  = tid & 3;
    const int bgs = bg ^ ((br >> 1) & 3);   // invariant under +128
    const char* bHi0 = (const char*)(Bhi + (size_t)(colB0 + br) * DMODEL) + bgs * 16;
    const char* bHi1 = (const char*)(Bhi + (size_t)(colB0 + br + 128) * DMODEL) + bgs * 16;
    const char* bLo0 = (const char*)(Blo + (size_t)(colB0 + br) * DMODEL) + bgs * 16;
    const char* bLo1 = (const char*)(Blo + (size_t)(colB0 + br + 128) * DMODEL) + bgs * 16;

#define STAGE_QA(tt)                                                                 \
    do {                                                                             \
        const int _s = (tt) & 3;                                                     \
        const char* _ab = ((tt) < 64) ? aHiB : aLoB;                                 \
        const size_t _ko = (size_t)((tt) & 31) * 64;                                 \
        __builtin_amdgcn_global_load_lds(                                            \
            (const __attribute__((address_space(1))) void*)(_ab + _ko),              \
            (__attribute__((address_space(3))) void*)&As[_s][ar][ag * 8], 16, 0, 0); \
    } while (0)

#define STAGE_QB(tt)                                                                 \
    do {                                                                             \
        const int _s = (tt) & 3;                                                     \
        const bool _lo = ((tt) >= 32) && ((tt) < 64);                                \
        const char* _b0 = _lo ? bLo0 : bHi0;                                         \
        const char* _b1 = _lo ? bLo1 : bHi1;                                         \
        const size_t _ko = (size_t)((tt) & 31) * 64;                                 \
        __builtin_amdgcn_global_load_lds(                                            \
            (const __attribute__((address_space(1))) void*)(_b0 + _ko),              \
            (__attribute__((address_space(3))) void*)&Bs[_s][br][bg * 8], 16, 0, 0); \
        __builtin_amdgcn_global_load_lds(                                            \
            (const __attribute__((address_space(1))) void*)(_b1 + _ko),              \
            (__attribute__((address_space(3))) void*)&Bs[_s][br + 128][bg * 8], 16, 0, 0);\
    } while (0)

    const int fm = lane & 15;
    const int fq = lane >> 4;
    const int ck = (fq ^ ((fm >> 1) & 3)) * 8;

    floatx4 acc[4][4] = {};

    auto tile_body = [&](int t, bool do_stage) {
        const int s = t & 3;
        // phase A: read all A frags + B j=0..1; stage next A.
        half8 av[4], bv01[2];
#pragma unroll
        for (int i = 0; i < 4; ++i) av[i] = *(const half8*)&As[s][wm + i * 16 + fm][ck];
#pragma unroll
        for (int j = 0; j < 2; ++j) bv01[j] = *(const half8*)&Bs[s][wn + j * 16 + fm][ck];
        if (do_stage) STAGE_QA(t + 3);
        asm volatile("" ::: "memory");
        __builtin_amdgcn_s_barrier();
        asm volatile("" ::: "memory");
        __builtin_amdgcn_s_setprio(1);
#pragma unroll
        for (int i = 0; i < 4; ++i)
#pragma unroll
            for (int j = 0; j < 2; ++j)
                acc[i][j] = __builtin_amdgcn_mfma_f32_16x16x32_f16(av[i], bv01[j], acc[i][j], 0, 0, 0);
        __builtin_amdgcn_s_setprio(0);
        asm volatile("" ::: "memory");
        __builtin_amdgcn_s_barrier();
        asm volatile("" ::: "memory");
        // phase B: read B j=2..3; stage next B.
        half8 bv23[2];
#pragma unroll
        for (int j = 0; j < 2; ++j) bv23[j] = *(const half8*)&Bs[s][wn + 32 + j * 16 + fm][ck];
        if (do_stage) STAGE_QB(t + 3);
        asm volatile("" ::: "memory");
        __builtin_amdgcn_s_barrier();
        asm volatile("" ::: "memory");
        __builtin_amdgcn_s_setprio(1);
#pragma unroll
        for (int i = 0; i < 4; ++i)
#pragma unroll
            for (int j = 0; j < 2; ++j)
                acc[i][j + 2] = __builtin_amdgcn_mfma_f32_16x16x32_f16(av[i], bv23[j], acc[i][j + 2], 0, 0, 0);
        __builtin_amdgcn_s_setprio(0);
    };

    // Prologue: stage tiles 0,1,2 (9 instrs); gate on tile 0 (6 outstanding).
    STAGE_QA(0); STAGE_QB(0);
    STAGE_QA(1); STAGE_QB(1);
    STAGE_QA(2); STAGE_QB(2);
    asm volatile("s_waitcnt vmcnt(6)" ::: "memory");
    __builtin_amdgcn_s_barrier();
    asm volatile("" ::: "memory");

    // 96 virtual K-tiles (3 segments x 32).
#pragma unroll 1
    for (int t = 0; t < 93; ++t) {
        tile_body(t, true);
        asm volatile("s_waitcnt vmcnt(6)" ::: "memory");
        __builtin_amdgcn_s_barrier();
        asm volatile("" ::: "memory");
    }
    tile_body(93, false);
    asm volatile("s_waitcnt vmcnt(3)" ::: "memory");
    __builtin_amdgcn_s_barrier();
    asm volatile("" ::: "memory");
    tile_body(94, false);
    asm volatile("s_waitcnt vmcnt(0)" ::: "memory");
    __builtin_amdgcn_s_barrier();
    asm volatile("" ::: "memory");
    tile_body(95, false);
#undef STAGE_QA
#undef STAGE_QB

    _Float16* dcat = Qcat;
    int cbase = colB0;
    if (colB0 >= 1024) { dcat = Kcat; cbase = colB0 - 1024; }

#pragma unroll
    for (int i = 0; i < 4; ++i) {
        const int growb = rowA0 + wm + i * 16 + fq * 4;
#pragma unroll
        for (int j = 0; j < 4; ++j) {
            const int gcol = wn + j * 16 + fm;
#pragma unroll
            for (int r = 0; r < 4; ++r) {
                float v = acc[i][j][r];
                size_t idx = (size_t)(growb + r) * 2048 + cbase + gcol;
                _Float16 h, l;
                split_val(v, h, l);
                dcat[idx] = h;
                dcat[idx + 1024] = l;
            }
        }
    }
}

// ---------------------------------------------------------------------------
// Score GEMM, deep-pipelined (unchanged structure, + XCD swizzle):
// S = Qcat @ Kcat^T (fp16, K=2048), tile 256x256, BK=32, 8 waves,
// 4-slot ring, vmcnt(8) gating, tile-softmax epilogue.
// ---------------------------------------------------------------------------
__global__ __launch_bounds__(512, 2) void gemm_score_dp(
    const _Float16* __restrict__ Qc,   // [4096][2048]
    const _Float16* __restrict__ Kc,   // [4096][2048]
    _Float16* __restrict__ Ph, float* __restrict__ Marr, float* __restrict__ Larr,
    float scale) {
    __shared__ _Float16 As[4][256][32];   // 64 KB
    __shared__ _Float16 Bs[4][256][32];   // 64 KB

    const int tid  = threadIdx.x;
    const int lane = tid & 63;
    const int wid  = tid >> 6;
    const int wm   = (wid >> 2) * 128;    // 0 or 128
    const int wn   = (wid & 3) * 64;      // 0,64,128,192

    // XCD-aware bijective swizzle: nwg = 256 (grid 16 x 16).
    const int lin = blockIdx.y * 16 + blockIdx.x;
    const int swz = (lin & 7) * 32 + (lin >> 3);
    const int rowA0 = (swz >> 4) * 256;
    const int colB0 = (swz & 15) * 256;

    const int pr  = tid >> 2;
    const int pg  = tid & 3;
    const int pgs = pg ^ ((pr >> 1) & 3);

    const char* aSrc0 = (const char*)(Qc + (size_t)(rowA0 + pr) * 2048) + pgs * 16;
    const char* aSrc1 = (const char*)(Qc + (size_t)(rowA0 + pr + 128) * 2048) + pgs * 16;
    const char* bSrc0 = (const char*)(Kc + (size_t)(colB0 + pr) * 2048) + pgs * 16;
    const char* bSrc1 = (const char*)(Kc + (size_t)(colB0 + pr + 128) * 2048) + pgs * 16;

#define STAGE_A(t)                                                                  \
    do {                                                                            \
        const int _s = (t) & 3;                                                     \
        const size_t _ko = (size_t)(t) * 64;                                        \
        __builtin_amdgcn_global_load_lds(                                           \
            (const __attribute__((address_space(1))) void*)(aSrc0 + _ko),           \
            (__attribute__((address_space(3))) void*)&As[_s][pr][pg * 8], 16, 0, 0);\
        __builtin_amdgcn_global_load_lds(                                           \
            (const __attribute__((address_space(1))) void*)(aSrc1 + _ko),           \
            (__attribute__((address_space(3))) void*)&As[_s][pr + 128][pg * 8], 16, 0, 0);\
    } while (0)

#define STAGE_B(t)                                                                  \
    do {                                                                            \
        const int _s = (t) & 3;                                                     \
        const size_t _ko = (size_t)(t) * 64;                                        \
        __builtin_amdgcn_global_load_lds(                                           \
            (const __attribute__((address_space(1))) void*)(bSrc0 + _ko),           \
            (__attribute__((address_space(3))) void*)&Bs[_s][pr][pg * 8], 16, 0, 0);\
        __builtin_amdgcn_global_load_lds(                                           \
            (const __attribute__((address_space(1))) void*)(bSrc1 + _ko),           \
            (__attribute__((address_space(3))) void*)&Bs[_s][pr + 128][pg * 8], 16, 0, 0);\
    } while (0)

    const int fm = lane & 15;
    const int fq = lane >> 4;
    const int ck = (fq ^ ((fm >> 1) & 3)) * 8;

    floatx4 acc[8][4] = {};

    auto tile_body = [&](int t, bool do_stage) {
        const int s = t & 3;
        half8 av[4], bv[4];
#pragma unroll
        for (int i = 0; i < 4; ++i) av[i] = *(const half8*)&As[s][wm + i * 16 + fm][ck];
#pragma unroll
        for (int j = 0; j < 4; ++j) bv[j] = *(const half8*)&Bs[s][wn + j * 16 + fm][ck];
        if (do_stage) STAGE_A(t + 3);
        asm volatile("" ::: "memory");
        __builtin_amdgcn_s_barrier();
        asm volatile("" ::: "memory");
        __builtin_amdgcn_s_setprio(1);
#pragma unroll
        for (int i = 0; i < 4; ++i)
#pragma unroll
            for (int j = 0; j < 4; ++j)
                acc[i][j] = __builtin_amdgcn_mfma_f32_16x16x32_f16(av[i], bv[j], acc[i][j], 0, 0, 0);
        __builtin_amdgcn_s_setprio(0);
        asm volatile("" ::: "memory");
        __builtin_amdgcn_s_barrier();
        asm volatile("" ::: "memory");
        half8 av2[4];
#pragma unroll
        for (int i = 0; i < 4; ++i) av2[i] = *(const half8*)&As[s][wm + 64 + i * 16 + fm][ck];
        if (do_stage) STAGE_B(t + 3);
        asm volatile("" ::: "memory");
        __builtin_amdgcn_s_barrier();
        asm volatile("" ::: "memory");
        __builtin_amdgcn_s_setprio(1);
#pragma unroll
        for (int i = 0; i < 4; ++i)
#pragma unroll
            for (int j = 0; j < 4; ++j)
                acc[i + 4][j] = __builtin_amdgcn_mfma_f32_16x16x32_f16(av2[i], bv[j], acc[i + 4][j], 0, 0, 0);
        __builtin_amdgcn_s_setprio(0);
    };

    STAGE_A(0); STAGE_B(0);
    STAGE_A(1); STAGE_B(1);
    STAGE_A(2); STAGE_B(2);
    asm volatile("s_waitcnt vmcnt(8)" ::: "memory");
    __builtin_amdgcn_s_barrier();
    asm volatile("" ::: "memory");

#pragma unroll 1
    for (int t = 0; t < 61; ++t) {
        tile_body(t, true);
        asm volatile("s_waitcnt vmcnt(8)" ::: "memory");
        __builtin_amdgcn_s_barrier();
        asm volatile("" ::: "memory");
    }
    tile_body(61, false);
    asm volatile("s_waitcnt vmcnt(4)" ::: "memory");
    __builtin_amdgcn_s_barrier();
    asm volatile("" ::: "memory");
    tile_body(62, false);
    asm volatile("s_waitcnt vmcnt(0)" ::: "memory");
    __builtin_amdgcn_s_barrier();
    asm volatile("" ::: "memory");
    tile_body(63, false);
#undef STAGE_A
#undef STAGE_B

    const int tprime = (colB0 + wn) >> 6;
#pragma unroll
    for (int i = 0; i < 8; ++i) {
#pragma unroll
        for (int r = 0; r < 4; ++r) {
            const int grow = rowA0 + wm + i * 16 + fq * 4 + r;
            float s0 = acc[i][0][r] * scale;
            float s1 = acc[i][1][r] * scale;
            float s2 = acc[i][2][r] * scale;
            float s3 = acc[i][3][r] * scale;
            float mx = fmaxf(fmaxf(s0, s1), fmaxf(s2, s3));
            mx = fmaxf(mx, __shfl_xor(mx, 1));
            mx = fmaxf(mx, __shfl_xor(mx, 2));
            mx = fmaxf(mx, __shfl_xor(mx, 4));
            mx = fmaxf(mx, __shfl_xor(mx, 8));
            float p0 = __expf(s0 - mx);
            float p1 = __expf(s1 - mx);
            float p2 = __expf(s2 - mx);
            float p3 = __expf(s3 - mx);
            float sum = p0 + p1 + p2 + p3;
            sum += __shfl_xor(sum, 1);
            sum += __shfl_xor(sum, 2);
            sum += __shfl_xor(sum, 4);
            sum += __shfl_xor(sum, 8);
            _Float16* prow = Ph + (size_t)grow * SEQ + colB0 + wn + fm;
            prow[0]  = (_Float16)p0;
            prow[16] = (_Float16)p1;
            prow[32] = (_Float16)p2;
            prow[48] = (_Float16)p3;
            if (fm == 0) {
                Marr[(size_t)grow * 64 + tprime] = mx;
                Larr[(size_t)grow * 64 + tprime] = sum;
            }
        }
    }
}

// ---------------------------------------------------------------------------
// Per-row finalize: wave 0 computes m*, L, c_t = e^(m_t-m*)/L into LDS;
// all 256 threads rescale the row's 4096 fp16 P values in place.
// ---------------------------------------------------------------------------
__global__ __launch_bounds__(256) void reduce_scale(const float* __restrict__ Marr,
                                                    const float* __restrict__ Larr,
                                                    _Float16* __restrict__ P) {
    __shared__ float c_tab[64];
    const int tid = threadIdx.x;
    const int row = blockIdx.x;

    if (tid < 64) {
        float mt = Marr[(size_t)row * 64 + tid];
        float lt = Larr[(size_t)row * 64 + tid];
        float m = mt;
#pragma unroll
        for (int off = 32; off > 0; off >>= 1) m = fmaxf(m, __shfl_xor(m, off));
        float contrib = lt * __expf(mt - m);
        float L = contrib;
#pragma unroll
        for (int off = 32; off > 0; off >>= 1) L += __shfl_xor(L, off);
        c_tab[tid] = __expf(mt - m) / L;
    }
    __syncthreads();

    _Float16* prow = P + (size_t)row * SEQ;
#pragma unroll
    for (int i = 0; i < 4; ++i) {
        const int col = i * 1024 + (tid << 2);
        const _Float16 c = (_Float16)c_tab[col >> 6];
        half4v v = *(const half4v*)(prow + col);
        v[0] *= c; v[1] *= c; v[2] *= c; v[3] *= c;
        *(half4v*)(prow + col) = v;
    }
}

// ---------------------------------------------------------------------------
// PV GEMM, deep-pipelined: out = P @ V (fp16 in, fp32 out), A=P [4096][4096],
// B=VT [1024][4096] (B row = output col). Tile 128(M)x128(N), BK=64,
// 8 waves (2Mx4N), per-wave 64x32 (acc[4][2]). 4-slot ring
// (A 16KB + B 16KB per slot = 128KB), 4 vmem instrs/tile, gate vmcnt(8).
// LDS rows are 128B -> granule-XOR swizzle: physical granule g holds logical
// kgran g ^ (row&7); staged from pre-swizzled global source, read at
// g = (slice*4+fq) ^ (fm&7). 8 lanes per granule column = BW-optimal.
// ---------------------------------------------------------------------------
__global__ __launch_bounds__(512, 1) void gemm_pv_dp(
    const _Float16* __restrict__ P,    // [4096][4096]
    const _Float16* __restrict__ VT,   // [1024][4096]
    float* __restrict__ out) {         // [4096][1024]
    __shared__ _Float16 As[4][128][64];   // 64 KB
    __shared__ _Float16 Bs[4][128][64];   // 64 KB

    const int tid  = threadIdx.x;
    const int lane = tid & 63;
    const int wid  = tid >> 6;
    const int wm   = (wid >> 2) * 64;     // 0,64
    const int wn   = (wid & 3) * 32;      // 0,32,64,96

    // XCD-aware bijective swizzle: nwg = 256 (grid 8 x 32).
    const int lin = blockIdx.y * 8 + blockIdx.x;
    const int swz = (lin & 7) * 32 + (lin >> 3);
    const int rowA0 = (swz >> 3) * 128;
    const int colB0 = (swz & 7) * 128;

    // Staging: 1024 granules per operand tile (128 rows x 8), 2 per thread
    // (rows r, r+64). Source k-granule pre-swizzled: ags = g ^ (row&7),
    // invariant under row+64.
    const int prow = tid >> 3;            // 0..63
    const int pgr  = tid & 7;
    const int ags  = pgr ^ (prow & 7);
    const char* aSrc0 = (const char*)(P  + (size_t)(rowA0 + prow) * SEQ) + ags * 16;
    const char* aSrc1 = (const char*)(P  + (size_t)(rowA0 + prow + 64) * SEQ) + ags * 16;
    const char* bSrc0 = (const char*)(VT + (size_t)(colB0 + prow) * SEQ) + ags * 16;
    const char* bSrc1 = (const char*)(VT + (size_t)(colB0 + prow + 64) * SEQ) + ags * 16;

#define STAGE_PA(tt)                                                                \
    do {                                                                            \
        const int _s = (tt) & 3;                                                    \
        const size_t _ko = (size_t)(tt) * 128;                                      \
        __builtin_amdgcn_global_load_lds(                                           \
            (const __attribute__((address_space(1))) void*)(aSrc0 + _ko),           \
            (__attribute__((address_space(3))) void*)&As[_s][prow][pgr * 8], 16, 0, 0);\
        __builtin_amdgcn_global_load_lds(                                           \
            (const __attribute__((address_space(1))) void*)(aSrc1 + _ko),           \
            (__attribute__((address_space(3))) void*)&As[_s][prow + 64][pgr * 8], 16, 0, 0);\
    } while (0)

#define STAGE_PB(tt)                                                                \
    do {                                                                            \
        const int _s = (tt) & 3;                                                    \
        const size_t _ko = (size_t)(tt) * 128;                                      \
        __builtin_amdgcn_global_load_lds(                                           \
            (const __attribute__((address_space(1))) void*)(bSrc0 + _ko),           \
            (__attribute__((address_space(3))) void*)&Bs[_s][prow][pgr * 8], 16, 0, 0);\
        __builtin_amdgcn_global_load_lds(                                           \
            (const __attribute__((address_space(1))) void*)(bSrc1 + _ko),           \
            (__attribute__((address_space(3))) void*)&Bs[_s][prow + 64][pgr * 8], 16, 0, 0);\
    } while (0)

    const int fm = lane & 15;
    const int fq = lane >> 4;
    const int ck0 = ((fq    ) ^ (fm & 7)) * 8;   // k-slice 0 (k0..k0+31)
    const int ck1 = ((fq + 4) ^ (fm & 7)) * 8;   // k-slice 1 (k0+32..k0+63)

    floatx4 acc[4][2] = {};

    auto tile_body = [&](int t, bool do_stage) {
        const int s = t & 3;
        // phase A: k-slice 0
        half8 av[4], bv[2];
#pragma unroll
        for (int i = 0; i < 4; ++i) av[i] = *(const half8*)&As[s][wm + i * 16 + fm][ck0];
#pragma unroll
        for (int j = 0; j < 2; ++j) bv[j] = *(const half8*)&Bs[s][wn + j * 16 + fm][ck0];
        if (do_stage) STAGE_PA(t + 3);
        asm volatile("" ::: "memory");
        __builtin_amdgcn_s_barrier();
        asm volatile("" ::: "memory");
        __builtin_amdgcn_s_setprio(1);
#pragma unroll
        for (int i = 0; i < 4; ++i)
#pragma unroll
            for (int j = 0; j < 2; ++j)
                acc[i][j] = __builtin_amdgcn_mfma_f32_16x16x32_f16(av[i], bv[j], acc[i][j], 0, 0, 0);
        __builtin_amdgcn_s_setprio(0);
        asm volatile("" ::: "memory");
        __builtin_amdgcn_s_barrier();
        asm volatile("" ::: "memory");
        // phase B: k-slice 1
        half8 av2[4], bv2[2];
#pragma unroll
        for (int i = 0; i < 4; ++i) av2[i] = *(const half8*)&As[s][wm + i * 16 + fm][ck1];
#pragma unroll
        for (int j = 0; j < 2; ++j) bv2[j] = *(const half8*)&Bs[s][wn + j * 16 + fm][ck1];
        if (do_stage) STAGE_PB(t + 3);
        asm volatile("" ::: "memory");
        __builtin_amdgcn_s_barrier();
        asm volatile("" ::: "memory");
        __builtin_amdgcn_s_setprio(1);
#pragma unroll
        for (int i = 0; i < 4; ++i)
#pragma unroll
            for (int j = 0; j < 2; ++j)
                acc[i][j] = __builtin_amdgcn_mfma_f32_16x16x32_f16(av2[i], bv2[j], acc[i][j], 0, 0, 0);
        __builtin_amdgcn_s_setprio(0);
    };

    STAGE_PA(0); STAGE_PB(0);
    STAGE_PA(1); STAGE_PB(1);
    STAGE_PA(2); STAGE_PB(2);
    asm volatile("s_waitcnt vmcnt(8)" ::: "memory");
    __builtin_amdgcn_s_barrier();
    asm volatile("" ::: "memory");

    // 64 K-tiles (K = 4096, BK = 64).
#pragma unroll 1
    for (int t = 0; t < 61; ++t) {
        tile_body(t, true);
        asm volatile("s_waitcnt vmcnt(8)" ::: "memory");
        __builtin_amdgcn_s_barrier();
        asm volatile("" ::: "memory");
    }
    tile_body(61, false);
    asm volatile("s_waitcnt vmcnt(4)" ::: "memory");
    __builtin_amdgcn_s_barrier();
    asm volatile("" ::: "memory");
    tile_body(62, false);
    asm volatile("s_waitcnt vmcnt(0)" ::: "memory");
    __builtin_amdgcn_s_barrier();
    asm volatile("" ::: "memory");
    tile_body(63, false);
#undef STAGE_PA
#undef STAGE_PB

#pragma unroll
    for (int i = 0; i < 4; ++i) {
        const int growb = rowA0 + wm + i * 16 + fq * 4;
#pragma unroll
        for (int j = 0; j < 2; ++j) {
            const int gcol = colB0 + wn + j * 16 + fm;
#pragma unroll
            for (int r = 0; r < 4; ++r)
                out[(size_t)(growb + r) * DMODEL + gcol] = acc[i][j][r];
        }
    }
}

// ---------------------------------------------------------------------------
// Plain fp16 MFMA GEMM, tile 128x64 (16x16x32): V-projection only now.
// ---------------------------------------------------------------------------
template <int OUT_HALF>
__global__ __launch_bounds__(256) void gemm_h16_n64(
    const _Float16* __restrict__ A, int lda,
    const _Float16* __restrict__ B, int ldb,
    float* __restrict__ Cf, _Float16* __restrict__ Ch,
    int N, int K) {
    __shared__ _Float16 Ah[128][32];
    __shared__ _Float16 Bh[64][32];

    const int tid = threadIdx.x;
    const int lane = tid & 63;
    const int w = tid >> 6;
    const int wm = (w >> 1) * 64;
    const int wn = (w & 1) * 32;

    const int rowA0 = blockIdx.y * 128;
    const int colB0 = blockIdx.x * 64;

    const int sr = lane >> 2;
    const int sc = lane & 3;
    const int ra0 = w * 32 + sr;
    const int ra1 = ra0 + 16;
    const int rb0 = w * 16 + sr;
    const int cga0 = sc ^ ((ra0 >> 1) & 3);
    const int cga1 = sc ^ ((ra1 >> 1) & 3);
    const int cgb0 = sc ^ ((rb0 >> 1) & 3);

    const char* gp[3];
    gp[0] = (const char*)(A + (size_t)(rowA0 + ra0) * lda) + cga0 * 16;
    gp[1] = (const char*)(A + (size_t)(rowA0 + ra1) * lda) + cga1 * 16;
    gp[2] = (const char*)(B + (size_t)(colB0 + rb0) * ldb) + cgb0 * 16;

    _Float16* lp[3] = {
        &Ah[w * 32][0], &Ah[w * 32 + 16][0],
        &Bh[w * 16][0],
    };

    const int fm = lane & 15;
    const int fq = lane >> 4;
    const int ck = ((fq ^ ((fm >> 1) & 3)) * 8);

    floatx4 acc[4][2] = {};

    for (int k0 = 0; k0 < K; k0 += 32) {
#pragma unroll
        for (int t = 0; t < 3; ++t)
            __builtin_amdgcn_global_load_lds(
                (const __attribute__((address_space(1))) void*)gp[t],
                (__attribute__((address_space(3))) void*)lp[t], 16, 0, 0);
#pragma unroll
        for (int t = 0; t < 3; ++t) gp[t] += 64;
        __syncthreads();

        half8 av[4], bv[2];
#pragma unroll
        for (int i = 0; i < 4; ++i)
            av[i] = *(const half8*)&Ah[wm + i * 16 + fm][ck];
#pragma unroll
        for (int j = 0; j < 2; ++j)
            bv[j] = *(const half8*)&Bh[wn + j * 16 + fm][ck];
#pragma unroll
        for (int i = 0; i < 4; ++i)
#pragma unroll
            for (int j = 0; j < 2; ++j)
                acc[i][j] = __builtin_amdgcn_mfma_f32_16x16x32_f16(av[i], bv[j], acc[i][j], 0, 0, 0);
        __syncthreads();
    }

#pragma unroll
    for (int i = 0; i < 4; ++i) {
        const int growb = rowA0 + wm + i * 16 + fq * 4;
#pragma unroll
        for (int j = 0; j < 2; ++j) {
            const int gcol = colB0 + wn + j * 16 + fm;
#pragma unroll
            for (int r = 0; r < 4; ++r) {
                float v = acc[i][j][r];
                size_t idx = (size_t)(growb + r) * N + gcol;
                if (OUT_HALF) Ch[idx] = (_Float16)v;
                else          Cf[idx] = v;
            }
        }
    }
}

// ---------------------------------------------------------------------------
// Workspace layout (104 MB used):
//  [0,32M)   P fp16 [4096][4096] (region reused: x_hi [0,8M), x_lo [8,16M),
//            wqkT_hi [16,20M), wqkT_lo [20,24M), wvT [24,26M) all dead
//            before the score kernel writes P)
//  [32,33M)  Marr fp32 [4096][64]   [33,34M) Larr fp32 [4096][64]
//  [64,80M)  Qcat fp16 [4096][2048] (hi cols 0..1023, lo cols 1024..2047)
//  [80,96M)  Kcat fp16 [4096][2048]
//  [96,104M) VT fp16 [1024][4096]
// ---------------------------------------------------------------------------
extern "C" void kernel_launch(void* const* d_in, const int* in_sizes, int n_in,
                              void* d_out, int out_size, void* d_ws, size_t ws_size,
                              hipStream_t stream) {
    const float* x  = (const float*)d_in[0];
    const float* wq = (const float*)d_in[1];
    const float* wk = (const float*)d_in[2];
    const float* wv = (const float*)d_in[3];
    float* out = (float*)d_out;

    char* base = (char*)d_ws;
    const size_t MB = 1u << 20;
    _Float16* P       = (_Float16*)base;               // [4096][4096]
    _Float16* x_hi    = (_Float16*)(base + 0 * MB);
    _Float16* x_lo    = (_Float16*)(base + 8 * MB);
    _Float16* wqkT_hi = (_Float16*)(base + 16 * MB);   // [2048][1024]
    _Float16* wqkT_lo = (_Float16*)(base + 20 * MB);
    _Float16* wvT     = (_Float16*)(base + 24 * MB);   // [1024][1024]
    float*    Marr    = (float*)(base + 32 * MB);
    float*    Larr    = (float*)(base + 33 * MB);
    _Float16* Qcat    = (_Float16*)(base + 64 * MB);   // [4096][2048]
    _Float16* Kcat    = (_Float16*)(base + 80 * MB);   // [4096][2048]
    _Float16* VT      = (_Float16*)(base + 96 * MB);   // [1024][4096]

    // 1) fused prep
    prep<<<4096, 256, 0, stream>>>(x, wq, wk, wv, x_hi, x_lo, wqkT_hi, wqkT_lo, wvT);

    // 2) QK projection, deep-pipelined (exact 3-product via virtual K=3072)
    dim3 gqk(2048 / 256, SEQ / 128);   // (8,32)
    gemm_qkproj_dp<<<gqk, dim3(512), 0, stream>>>(x_hi, x_lo, wqkT_hi, wqkT_lo,
                                                  Qcat, Kcat);
    // V^T = wv^T @ x^T, plain fp16, tile 128x64
    dim3 gvt(SEQ / 64, DMODEL / 128);  // (64,8)
    gemm_h16_n64<1><<<gvt, 256, 0, stream>>>(wvT, DMODEL, x_hi, DMODEL,
                                             nullptr, VT, SEQ, DMODEL);

    // 3) scores + tile-softmax, deep-pipelined 256x256 K=2048
    dim3 gs(SEQ / 256, SEQ / 256);     // (16,16)
    gemm_score_dp<<<gs, dim3(512), 0, stream>>>(Qcat, Kcat, P, Marr, Larr,
                                                1.0f / 32.0f);

    // 4) finalize: P *= c_t(row)  (in place, exact softmax)
    reduce_scale<<<SEQ, 256, 0, stream>>>(Marr, Larr, P);

    // 5) out = P @ V, deep-pipelined
    dim3 gpv(DMODEL / 128, SEQ / 128); // (8,32)
    gemm_pv_dp<<<gpv, dim3(512), 0, stream>>>(P, VT, out);
}

// Round 4
// 295.875 us; speedup vs baseline: 1.1928x; 1.0247x over previous
//
#include <hip/hip_runtime.h>
#include <hip/hip_fp16.h>
#include <math.h>

#define SEQ    4096
#define DMODEL 1024

typedef _Float16 half8   __attribute__((ext_vector_type(8)));
typedef _Float16 half4v  __attribute__((ext_vector_type(4)));
typedef float    floatx4 __attribute__((ext_vector_type(4)));

__device__ inline void split_val(float v, _Float16& h, _Float16& l) {
    _Float16 hh = (_Float16)v;
    h = hh;
    l = (_Float16)(v - (float)hh);
}

// ---------------------------------------------------------------------------
// Fused prep: blocks 0..3071 transpose wq/wk/wv (32x32 tiles); blocks
// 3072..4095 split x into hi/lo fp16 (4 float4 per thread = full x).
// ---------------------------------------------------------------------------
__global__ __launch_bounds__(256) void prep(const float* __restrict__ x,
                                            const float* __restrict__ wq,
                                            const float* __restrict__ wk,
                                            const float* __restrict__ wv,
                                            _Float16* __restrict__ x_hi,
                                            _Float16* __restrict__ x_lo,
                                            _Float16* __restrict__ wqkT_hi,
                                            _Float16* __restrict__ wqkT_lo,
                                            _Float16* __restrict__ wvT) {
    __shared__ float tile[32][33];
    const int b = blockIdx.x;
    if (b < 3072) {
        const int which = b >> 10;           // 0=wq 1=wk 2=wv
        const int bb = b & 1023;
        const int c0 = (bb & 31) * 32;
        const int r0 = (bb >> 5) * 32;
        const float* w = (which == 0) ? wq : (which == 1) ? wk : wv;
        const int tx = threadIdx.x & 31, ty = threadIdx.x >> 5;
#pragma unroll
        for (int j = 0; j < 4; ++j)
            tile[ty * 4 + j][tx] = w[(size_t)(r0 + ty * 4 + j) * DMODEL + c0 + tx];
        __syncthreads();
        if (which < 2) {
            _Float16* th = wqkT_hi + (size_t)which * DMODEL * DMODEL;
            _Float16* tl = wqkT_lo + (size_t)which * DMODEL * DMODEL;
#pragma unroll
            for (int j = 0; j < 4; ++j) {
                float v = tile[tx][ty * 4 + j];
                size_t idx = (size_t)(c0 + ty * 4 + j) * DMODEL + r0 + tx;
                _Float16 h, l;
                split_val(v, h, l);
                th[idx] = h;
                tl[idx] = l;
            }
        } else {
#pragma unroll
            for (int j = 0; j < 4; ++j)
                wvT[(size_t)(c0 + ty * 4 + j) * DMODEL + r0 + tx] =
                    (_Float16)tile[tx][ty * 4 + j];
        }
    } else {
        const int t0 = (b - 3072) * 256 + threadIdx.x;
#pragma unroll
        for (int rep = 0; rep < 4; ++rep) {
            const size_t i = (size_t)t0 + (size_t)rep * 262144;
            floatx4 v = *(const floatx4*)(x + 4 * i);
            half4v h, l;
#pragma unroll
            for (int j = 0; j < 4; ++j) {
                _Float16 hh = (_Float16)v[j];
                _Float16 ll = (_Float16)(v[j] - (float)hh);
                h[j] = hh;
                l[j] = ll;
            }
            *(half4v*)(x_hi + 4 * i) = h;
            *(half4v*)(x_lo + 4 * i) = l;
        }
    }
}

// ---------------------------------------------------------------------------
// QK projection, deep-pipelined, MERGED single phase per K-tile (16 MFMA
// between one barrier pair — R3's 2x8 split left the matrix pipe idle vs
// the per-phase overhead). Virtual K=3072: seg0 x_hi·w_hi, seg1 x_hi·w_lo,
// seg2 x_lo·w_hi (exact 3-product). Tile 128x256, BK=32, 8 waves (2Mx4N).
// 4-slot ring (A 8KB + B 16KB = 24KB/slot = 96KB), 3 vmem/tile, gate
// vmcnt(6). No blockIdx swizzle: gridDim.x=8 -> XCD = col-panel, so each
// XCD's wqkT slab (~1MB hi+lo) is L2-resident; x streams via L3.
// Epilogue: split_val -> Qcat/Kcat [4096][2048].
// ---------------------------------------------------------------------------
__global__ __launch_bounds__(512, 1) void gemm_qkproj_dp(
    const _Float16* __restrict__ Ahi, const _Float16* __restrict__ Alo,   // x_hi/x_lo [4096][1024]
    const _Float16* __restrict__ Bhi, const _Float16* __restrict__ Blo,   // wqkT_hi/lo [2048][1024]
    _Float16* __restrict__ Qcat, _Float16* __restrict__ Kcat) {
    __shared__ _Float16 As[4][128][32];   // 32 KB
    __shared__ _Float16 Bs[4][256][32];   // 64 KB

    const int tid  = threadIdx.x;
    const int lane = tid & 63;
    const int wid  = tid >> 6;
    const int wm   = (wid >> 2) * 64;     // 0,64
    const int wn   = (wid & 3) * 64;      // 0,64,128,192

    const int rowA0 = blockIdx.y * 128;
    const int colB0 = blockIdx.x * 256;

    // A staging: 512 granules (128 rows x 4), 1 per thread.
    const int ar  = tid >> 2;
    const int ag  = tid & 3;
    const int ags = ag ^ ((ar >> 1) & 3);
    const char* aHiB = (const char*)(Ahi + (size_t)(rowA0 + ar) * DMODEL) + ags * 16;
    const char* aLoB = (const char*)(Alo + (size_t)(rowA0 + ar) * DMODEL) + ags * 16;
    // B staging: 1024 granules (256 rows x 4), 2 per thread (rows r, r+128).
    const int br  = tid >> 2;
    const int bg  = tid & 3;
    const int bgs = bg ^ ((br >> 1) & 3);   // invariant under +128
    const char* bHi0 = (const char*)(Bhi + (size_t)(colB0 + br) * DMODEL) + bgs * 16;
    const char* bHi1 = (const char*)(Bhi + (size_t)(colB0 + br + 128) * DMODEL) + bgs * 16;
    const char* bLo0 = (const char*)(Blo + (size_t)(colB0 + br) * DMODEL) + bgs * 16;
    const char* bLo1 = (const char*)(Blo + (size_t)(colB0 + br + 128) * DMODEL) + bgs * 16;

#define STAGE_QA(tt)                                                                 \
    do {                                                                             \
        const int _s = (tt) & 3;                                                     \
        const char* _ab = ((tt) < 64) ? aHiB : aLoB;                                 \
        const size_t _ko = (size_t)((tt) & 31) * 64;                                 \
        __builtin_amdgcn_global_load_lds(                                            \
            (const __attribute__((address_space(1))) void*)(_ab + _ko),              \
            (__attribute__((address_space(3))) void*)&As[_s][ar][ag * 8], 16, 0, 0); \
    } while (0)

#define STAGE_QB(tt)                                                                 \
    do {                                                                             \
        const int _s = (tt) & 3;                                                     \
        const bool _lo = ((tt) >= 32) && ((tt) < 64);                                \
        const char* _b0 = _lo ? bLo0 : bHi0;                                         \
        const char* _b1 = _lo ? bLo1 : bHi1;                                         \
        const size_t _ko = (size_t)((tt) & 31) * 64;                                 \
        __builtin_amdgcn_global_load_lds(                                            \
            (const __attribute__((address_space(1))) void*)(_b0 + _ko),              \
            (__attribute__((address_space(3))) void*)&Bs[_s][br][bg * 8], 16, 0, 0); \
        __builtin_amdgcn_global_load_lds(                                            \
            (const __attribute__((address_space(1))) void*)(_b1 + _ko),              \
            (__attribute__((address_space(3))) void*)&Bs[_s][br + 128][bg * 8], 16, 0, 0);\
    } while (0)

    const int fm = lane & 15;
    const int fq = lane >> 4;
    const int ck = (fq ^ ((fm >> 1) & 3)) * 8;

    floatx4 acc[4][4] = {};

    auto tile_body = [&](int t, bool do_stage) {
        const int s = t & 3;
        half8 av[4], bv[4];
#pragma unroll
        for (int i = 0; i < 4; ++i) av[i] = *(const half8*)&As[s][wm + i * 16 + fm][ck];
#pragma unroll
        for (int j = 0; j < 4; ++j) bv[j] = *(const half8*)&Bs[s][wn + j * 16 + fm][ck];
        if (do_stage) { STAGE_QA(t + 3); STAGE_QB(t + 3); }
        asm volatile("" ::: "memory");
        __builtin_amdgcn_s_barrier();
        asm volatile("" ::: "memory");
        __builtin_amdgcn_s_setprio(1);
#pragma unroll
        for (int i = 0; i < 4; ++i)
#pragma unroll
            for (int j = 0; j < 4; ++j)
                acc[i][j] = __builtin_amdgcn_mfma_f32_16x16x32_f16(av[i], bv[j], acc[i][j], 0, 0, 0);
        __builtin_amdgcn_s_setprio(0);
    };

    // Prologue: stage tiles 0,1,2 (9 instrs); gate on tile 0 (6 outstanding).
    STAGE_QA(0); STAGE_QB(0);
    STAGE_QA(1); STAGE_QB(1);
    STAGE_QA(2); STAGE_QB(2);
    asm volatile("s_waitcnt vmcnt(6)" ::: "memory");
    __builtin_amdgcn_s_barrier();
    asm volatile("" ::: "memory");

    // 96 virtual K-tiles (3 segments x 32).
#pragma unroll 1
    for (int t = 0; t < 93; ++t) {
        tile_body(t, true);
        asm volatile("s_waitcnt vmcnt(6)" ::: "memory");
        __builtin_amdgcn_s_barrier();
        asm volatile("" ::: "memory");
    }
    tile_body(93, false);
    asm volatile("s_waitcnt vmcnt(3)" ::: "memory");
    __builtin_amdgcn_s_barrier();
    asm volatile("" ::: "memory");
    tile_body(94, false);
    asm volatile("s_waitcnt vmcnt(0)" ::: "memory");
    __builtin_amdgcn_s_barrier();
    asm volatile("" ::: "memory");
    tile_body(95, false);
#undef STAGE_QA
#undef STAGE_QB

    _Float16* dcat = Qcat;
    int cbase = colB0;
    if (colB0 >= 1024) { dcat = Kcat; cbase = colB0 - 1024; }

#pragma unroll
    for (int i = 0; i < 4; ++i) {
        const int growb = rowA0 + wm + i * 16 + fq * 4;
#pragma unroll
        for (int j = 0; j < 4; ++j) {
            const int gcol = wn + j * 16 + fm;
#pragma unroll
            for (int r = 0; r < 4; ++r) {
                float v = acc[i][j][r];
                size_t idx = (size_t)(growb + r) * 2048 + cbase + gcol;
                _Float16 h, l;
                split_val(v, h, l);
                dcat[idx] = h;
                dcat[idx + 1024] = l;
            }
        }
    }
}

// ---------------------------------------------------------------------------
// Score GEMM, deep-pipelined (UNCHANGED from R3 — measured 81.4 us, 1688 TF):
// S = Qcat @ Kcat^T (fp16, K=2048), tile 256x256, BK=32, 8 waves,
// 4-slot ring, vmcnt(8) gating, tile-softmax epilogue.
// ---------------------------------------------------------------------------
__global__ __launch_bounds__(512, 2) void gemm_score_dp(
    const _Float16* __restrict__ Qc,   // [4096][2048]
    const _Float16* __restrict__ Kc,   // [4096][2048]
    _Float16* __restrict__ Ph, float* __restrict__ Marr, float* __restrict__ Larr,
    float scale) {
    __shared__ _Float16 As[4][256][32];   // 64 KB
    __shared__ _Float16 Bs[4][256][32];   // 64 KB

    const int tid  = threadIdx.x;
    const int lane = tid & 63;
    const int wid  = tid >> 6;
    const int wm   = (wid >> 2) * 128;    // 0 or 128
    const int wn   = (wid & 3) * 64;      // 0,64,128,192

    // XCD-aware bijective swizzle: nwg = 256 (grid 16 x 16).
    const int lin = blockIdx.y * 16 + blockIdx.x;
    const int swz = (lin & 7) * 32 + (lin >> 3);
    const int rowA0 = (swz >> 4) * 256;
    const int colB0 = (swz & 15) * 256;

    const int pr  = tid >> 2;
    const int pg  = tid & 3;
    const int pgs = pg ^ ((pr >> 1) & 3);

    const char* aSrc0 = (const char*)(Qc + (size_t)(rowA0 + pr) * 2048) + pgs * 16;
    const char* aSrc1 = (const char*)(Qc + (size_t)(rowA0 + pr + 128) * 2048) + pgs * 16;
    const char* bSrc0 = (const char*)(Kc + (size_t)(colB0 + pr) * 2048) + pgs * 16;
    const char* bSrc1 = (const char*)(Kc + (size_t)(colB0 + pr + 128) * 2048) + pgs * 16;

#define STAGE_A(t)                                                                  \
    do {                                                                            \
        const int _s = (t) & 3;                                                     \
        const size_t _ko = (size_t)(t) * 64;                                        \
        __builtin_amdgcn_global_load_lds(                                           \
            (const __attribute__((address_space(1))) void*)(aSrc0 + _ko),           \
            (__attribute__((address_space(3))) void*)&As[_s][pr][pg * 8], 16, 0, 0);\
        __builtin_amdgcn_global_load_lds(                                           \
            (const __attribute__((address_space(1))) void*)(aSrc1 + _ko),           \
            (__attribute__((address_space(3))) void*)&As[_s][pr + 128][pg * 8], 16, 0, 0);\
    } while (0)

#define STAGE_B(t)                                                                  \
    do {                                                                            \
        const int _s = (t) & 3;                                                     \
        const size_t _ko = (size_t)(t) * 64;                                        \
        __builtin_amdgcn_global_load_lds(                                           \
            (const __attribute__((address_space(1))) void*)(bSrc0 + _ko),           \
            (__attribute__((address_space(3))) void*)&Bs[_s][pr][pg * 8], 16, 0, 0);\
        __builtin_amdgcn_global_load_lds(                                           \
            (const __attribute__((address_space(1))) void*)(bSrc1 + _ko),           \
            (__attribute__((address_space(3))) void*)&Bs[_s][pr + 128][pg * 8], 16, 0, 0);\
    } while (0)

    const int fm = lane & 15;
    const int fq = lane >> 4;
    const int ck = (fq ^ ((fm >> 1) & 3)) * 8;

    floatx4 acc[8][4] = {};

    auto tile_body = [&](int t, bool do_stage) {
        const int s = t & 3;
        half8 av[4], bv[4];
#pragma unroll
        for (int i = 0; i < 4; ++i) av[i] = *(const half8*)&As[s][wm + i * 16 + fm][ck];
#pragma unroll
        for (int j = 0; j < 4; ++j) bv[j] = *(const half8*)&Bs[s][wn + j * 16 + fm][ck];
        if (do_stage) STAGE_A(t + 3);
        asm volatile("" ::: "memory");
        __builtin_amdgcn_s_barrier();
        asm volatile("" ::: "memory");
        __builtin_amdgcn_s_setprio(1);
#pragma unroll
        for (int i = 0; i < 4; ++i)
#pragma unroll
            for (int j = 0; j < 4; ++j)
                acc[i][j] = __builtin_amdgcn_mfma_f32_16x16x32_f16(av[i], bv[j], acc[i][j], 0, 0, 0);
        __builtin_amdgcn_s_setprio(0);
        asm volatile("" ::: "memory");
        __builtin_amdgcn_s_barrier();
        asm volatile("" ::: "memory");
        half8 av2[4];
#pragma unroll
        for (int i = 0; i < 4; ++i) av2[i] = *(const half8*)&As[s][wm + 64 + i * 16 + fm][ck];
        if (do_stage) STAGE_B(t + 3);
        asm volatile("" ::: "memory");
        __builtin_amdgcn_s_barrier();
        asm volatile("" ::: "memory");
        __builtin_amdgcn_s_setprio(1);
#pragma unroll
        for (int i = 0; i < 4; ++i)
#pragma unroll
            for (int j = 0; j < 4; ++j)
                acc[i + 4][j] = __builtin_amdgcn_mfma_f32_16x16x32_f16(av2[i], bv[j], acc[i + 4][j], 0, 0, 0);
        __builtin_amdgcn_s_setprio(0);
    };

    STAGE_A(0); STAGE_B(0);
    STAGE_A(1); STAGE_B(1);
    STAGE_A(2); STAGE_B(2);
    asm volatile("s_waitcnt vmcnt(8)" ::: "memory");
    __builtin_amdgcn_s_barrier();
    asm volatile("" ::: "memory");

#pragma unroll 1
    for (int t = 0; t < 61; ++t) {
        tile_body(t, true);
        asm volatile("s_waitcnt vmcnt(8)" ::: "memory");
        __builtin_amdgcn_s_barrier();
        asm volatile("" ::: "memory");
    }
    tile_body(61, false);
    asm volatile("s_waitcnt vmcnt(4)" ::: "memory");
    __builtin_amdgcn_s_barrier();
    asm volatile("" ::: "memory");
    tile_body(62, false);
    asm volatile("s_waitcnt vmcnt(0)" ::: "memory");
    __builtin_amdgcn_s_barrier();
    asm volatile("" ::: "memory");
    tile_body(63, false);
#undef STAGE_A
#undef STAGE_B

    const int tprime = (colB0 + wn) >> 6;
#pragma unroll
    for (int i = 0; i < 8; ++i) {
#pragma unroll
        for (int r = 0; r < 4; ++r) {
            const int grow = rowA0 + wm + i * 16 + fq * 4 + r;
            float s0 = acc[i][0][r] * scale;
            float s1 = acc[i][1][r] * scale;
            float s2 = acc[i][2][r] * scale;
            float s3 = acc[i][3][r] * scale;
            float mx = fmaxf(fmaxf(s0, s1), fmaxf(s2, s3));
            mx = fmaxf(mx, __shfl_xor(mx, 1));
            mx = fmaxf(mx, __shfl_xor(mx, 2));
            mx = fmaxf(mx, __shfl_xor(mx, 4));
            mx = fmaxf(mx, __shfl_xor(mx, 8));
            float p0 = __expf(s0 - mx);
            float p1 = __expf(s1 - mx);
            float p2 = __expf(s2 - mx);
            float p3 = __expf(s3 - mx);
            float sum = p0 + p1 + p2 + p3;
            sum += __shfl_xor(sum, 1);
            sum += __shfl_xor(sum, 2);
            sum += __shfl_xor(sum, 4);
            sum += __shfl_xor(sum, 8);
            _Float16* prow = Ph + (size_t)grow * SEQ + colB0 + wn + fm;
            prow[0]  = (_Float16)p0;
            prow[16] = (_Float16)p1;
            prow[32] = (_Float16)p2;
            prow[48] = (_Float16)p3;
            if (fm == 0) {
                Marr[(size_t)grow * 64 + tprime] = mx;
                Larr[(size_t)grow * 64 + tprime] = sum;
            }
        }
    }
}

// ---------------------------------------------------------------------------
// compute_c: per row, m* = max_t m_t, L = sum_t l_t e^(m_t-m*),
// c_t = e^(m_t-m*)/L, written TRANSPOSED as CarrT[64][4096] fp16 so the PV
// kernel can preload its 128-row slab with coalesced half8 loads.
// Replaces the old reduce_scale (which re-read+re-wrote all 32MB of P).
// ---------------------------------------------------------------------------
__global__ __launch_bounds__(64) void compute_c(const float* __restrict__ Marr,
                                                const float* __restrict__ Larr,
                                                _Float16* __restrict__ CarrT) {
    const int row = blockIdx.x;
    const int t = threadIdx.x;
    float mt = Marr[(size_t)row * 64 + t];
    float lt = Larr[(size_t)row * 64 + t];
    float m = mt;
#pragma unroll
    for (int off = 32; off > 0; off >>= 1) m = fmaxf(m, __shfl_xor(m, off));
    float e = __expf(mt - m);
    float L = lt * e;
#pragma unroll
    for (int off = 32; off > 0; off >>= 1) L += __shfl_xor(L, off);
    CarrT[(size_t)t * SEQ + row] = (_Float16)(e / L);
}

// ---------------------------------------------------------------------------
// PV GEMM, deep-pipelined, MERGED single phase per K-tile, with the softmax
// finalize scale folded in: out = sum_t c[row][t] * (P_t @ V_t). BK=64 tiles
// align exactly with the 64-col softmax spans, so c is one scalar per
// (A-row, tile) — applied to the A fp16 fragments (same rounding class as
// the old in-place fp16 rescale of P).
// Tile 128(M)x128(N), 8 waves (2Mx4N), per-wave 64x32 (acc[4][2]),
// 4-slot ring (32KB/slot = 128KB) + cT 16KB = 144KB LDS, 4 vmem/tile,
// gate vmcnt(8). No blockIdx swizzle: gridDim.x=8 -> XCD = col-panel,
// VT slab (1MB) L2-resident per XCD; P streams once via L3.
// ---------------------------------------------------------------------------
__global__ __launch_bounds__(512, 1) void gemm_pv_dp(
    const _Float16* __restrict__ P,      // [4096][4096] (unscaled exp)
    const _Float16* __restrict__ VT,     // [1024][4096]
    const _Float16* __restrict__ CarrT,  // [64][4096]
    float* __restrict__ out) {           // [4096][1024]
    __shared__ _Float16 As[4][128][64];   // 64 KB
    __shared__ _Float16 Bs[4][128][64];   // 64 KB
    __shared__ _Float16 cT[64][128];      // 16 KB

    const int tid  = threadIdx.x;
    const int lane = tid & 63;
    const int wid  = tid >> 6;
    const int wm   = (wid >> 2) * 64;     // 0,64
    const int wn   = (wid & 3) * 32;      // 0,32,64,96

    const int rowA0 = blockIdx.y * 128;
    const int colB0 = blockIdx.x * 128;

    // Preload this block's c slab: cT[t][r] = CarrT[t][rowA0+r].
    {
        int g = tid;
#pragma unroll
        for (int it = 0; it < 2; ++it, g += 512) {
            const int t  = g >> 4;
            const int r8 = (g & 15) * 8;
            *(half8*)&cT[t][r8] =
                *(const half8*)(CarrT + (size_t)t * SEQ + rowA0 + r8);
        }
    }
    __syncthreads();

    // Staging: 1024 granules per operand tile (128 rows x 8), 2 per thread
    // (rows r, r+64). Source k-granule pre-swizzled: ags = g ^ (row&7),
    // invariant under row+64.
    const int prow = tid >> 3;            // 0..63
    const int pgr  = tid & 7;
    const int ags  = pgr ^ (prow & 7);
    const char* aSrc0 = (const char*)(P  + (size_t)(rowA0 + prow) * SEQ) + ags * 16;
    const char* aSrc1 = (const char*)(P  + (size_t)(rowA0 + prow + 64) * SEQ) + ags * 16;
    const char* bSrc0 = (const char*)(VT + (size_t)(colB0 + prow) * SEQ) + ags * 16;
    const char* bSrc1 = (const char*)(VT + (size_t)(colB0 + prow + 64) * SEQ) + ags * 16;

#define STAGE_PA(tt)                                                                \
    do {                                                                            \
        const int _s = (tt) & 3;                                                    \
        const size_t _ko = (size_t)(tt) * 128;                                      \
        __builtin_amdgcn_global_load_lds(                                           \
            (const __attribute__((address_space(1))) void*)(aSrc0 + _ko),           \
            (__attribute__((address_space(3))) void*)&As[_s][prow][pgr * 8], 16, 0, 0);\
        __builtin_amdgcn_global_load_lds(                                           \
            (const __attribute__((address_space(1))) void*)(aSrc1 + _ko),           \
            (__attribute__((address_space(3))) void*)&As[_s][prow + 64][pgr * 8], 16, 0, 0);\
    } while (0)

#define STAGE_PB(tt)                                                                \
    do {                                                                            \
        const int _s = (tt) & 3;                                                    \
        const size_t _ko = (size_t)(tt) * 128;                                      \
        __builtin_amdgcn_global_load_lds(                                           \
            (const __attribute__((address_space(1))) void*)(bSrc0 + _ko),           \
            (__attribute__((address_space(3))) void*)&Bs[_s][prow][pgr * 8], 16, 0, 0);\
        __builtin_amdgcn_global_load_lds(                                           \
            (const __attribute__((address_space(1))) void*)(bSrc1 + _ko),           \
            (__attribute__((address_space(3))) void*)&Bs[_s][prow + 64][pgr * 8], 16, 0, 0);\
    } while (0)

    const int fm = lane & 15;
    const int fq = lane >> 4;
    const int ck0 = ((fq    ) ^ (fm & 7)) * 8;   // k-slice 0 (k0..k0+31)
    const int ck1 = ((fq + 4) ^ (fm & 7)) * 8;   // k-slice 1 (k0+32..k0+63)

    floatx4 acc[4][2] = {};

    auto tile_body = [&](int t, bool do_stage) {
        const int s = t & 3;
        half8 av[4], av2[4], bv[2], bv2[2];
        _Float16 cs[4];
#pragma unroll
        for (int i = 0; i < 4; ++i) {
            av[i]  = *(const half8*)&As[s][wm + i * 16 + fm][ck0];
            av2[i] = *(const half8*)&As[s][wm + i * 16 + fm][ck1];
            cs[i]  = cT[t][wm + i * 16 + fm];
        }
#pragma unroll
        for (int j = 0; j < 2; ++j) {
            bv[j]  = *(const half8*)&Bs[s][wn + j * 16 + fm][ck0];
            bv2[j] = *(const half8*)&Bs[s][wn + j * 16 + fm][ck1];
        }
#pragma unroll
        for (int i = 0; i < 4; ++i)
#pragma unroll
            for (int e = 0; e < 8; ++e) {
                av[i][e]  *= cs[i];
                av2[i][e] *= cs[i];
            }
        if (do_stage) { STAGE_PA(t + 3); STAGE_PB(t + 3); }
        asm volatile("" ::: "memory");
        __builtin_amdgcn_s_barrier();
        asm volatile("" ::: "memory");
        __builtin_amdgcn_s_setprio(1);
#pragma unroll
        for (int i = 0; i < 4; ++i)
#pragma unroll
            for (int j = 0; j < 2; ++j)
                acc[i][j] = __builtin_amdgcn_mfma_f32_16x16x32_f16(av[i], bv[j], acc[i][j], 0, 0, 0);
#pragma unroll
        for (int i = 0; i < 4; ++i)
#pragma unroll
            for (int j = 0; j < 2; ++j)
                acc[i][j] = __builtin_amdgcn_mfma_f32_16x16x32_f16(av2[i], bv2[j], acc[i][j], 0, 0, 0);
        __builtin_amdgcn_s_setprio(0);
    };

    STAGE_PA(0); STAGE_PB(0);
    STAGE_PA(1); STAGE_PB(1);
    STAGE_PA(2); STAGE_PB(2);
    asm volatile("s_waitcnt vmcnt(8)" ::: "memory");
    __builtin_amdgcn_s_barrier();
    asm volatile("" ::: "memory");

    // 64 K-tiles (K = 4096, BK = 64).
#pragma unroll 1
    for (int t = 0; t < 61; ++t) {
        tile_body(t, true);
        asm volatile("s_waitcnt vmcnt(8)" ::: "memory");
        __builtin_amdgcn_s_barrier();
        asm volatile("" ::: "memory");
    }
    tile_body(61, false);
    asm volatile("s_waitcnt vmcnt(4)" ::: "memory");
    __builtin_amdgcn_s_barrier();
    asm volatile("" ::: "memory");
    tile_body(62, false);
    asm volatile("s_waitcnt vmcnt(0)" ::: "memory");
    __builtin_amdgcn_s_barrier();
    asm volatile("" ::: "memory");
    tile_body(63, false);
#undef STAGE_PA
#undef STAGE_PB

#pragma unroll
    for (int i = 0; i < 4; ++i) {
        const int growb = rowA0 + wm + i * 16 + fq * 4;
#pragma unroll
        for (int j = 0; j < 2; ++j) {
            const int gcol = colB0 + wn + j * 16 + fm;
#pragma unroll
            for (int r = 0; r < 4; ++r)
                out[(size_t)(growb + r) * DMODEL + gcol] = acc[i][j][r];
        }
    }
}

// ---------------------------------------------------------------------------
// Plain fp16 MFMA GEMM, tile 128x64 (16x16x32): V-projection.
// ---------------------------------------------------------------------------
template <int OUT_HALF>
__global__ __launch_bounds__(256) void gemm_h16_n64(
    const _Float16* __restrict__ A, int lda,
    const _Float16* __restrict__ B, int ldb,
    float* __restrict__ Cf, _Float16* __restrict__ Ch,
    int N, int K) {
    __shared__ _Float16 Ah[128][32];
    __shared__ _Float16 Bh[64][32];

    const int tid = threadIdx.x;
    const int lane = tid & 63;
    const int w = tid >> 6;
    const int wm = (w >> 1) * 64;
    const int wn = (w & 1) * 32;

    const int rowA0 = blockIdx.y * 128;
    const int colB0 = blockIdx.x * 64;

    const int sr = lane >> 2;
    const int sc = lane & 3;
    const int ra0 = w * 32 + sr;
    const int ra1 = ra0 + 16;
    const int rb0 = w * 16 + sr;
    const int cga0 = sc ^ ((ra0 >> 1) & 3);
    const int cga1 = sc ^ ((ra1 >> 1) & 3);
    const int cgb0 = sc ^ ((rb0 >> 1) & 3);

    const char* gp[3];
    gp[0] = (const char*)(A + (size_t)(rowA0 + ra0) * lda) + cga0 * 16;
    gp[1] = (const char*)(A + (size_t)(rowA0 + ra1) * lda) + cga1 * 16;
    gp[2] = (const char*)(B + (size_t)(colB0 + rb0) * ldb) + cgb0 * 16;

    _Float16* lp[3] = {
        &Ah[w * 32][0], &Ah[w * 32 + 16][0],
        &Bh[w * 16][0],
    };

    const int fm = lane & 15;
    const int fq = lane >> 4;
    const int ck = ((fq ^ ((fm >> 1) & 3)) * 8);

    floatx4 acc[4][2] = {};

    for (int k0 = 0; k0 < K; k0 += 32) {
#pragma unroll
        for (int t = 0; t < 3; ++t)
            __builtin_amdgcn_global_load_lds(
                (const __attribute__((address_space(1))) void*)gp[t],
                (__attribute__((address_space(3))) void*)lp[t], 16, 0, 0);
#pragma unroll
        for (int t = 0; t < 3; ++t) gp[t] += 64;
        __syncthreads();

        half8 av[4], bv[2];
#pragma unroll
        for (int i = 0; i < 4; ++i)
            av[i] = *(const half8*)&Ah[wm + i * 16 + fm][ck];
#pragma unroll
        for (int j = 0; j < 2; ++j)
            bv[j] = *(const half8*)&Bh[wn + j * 16 + fm][ck];
#pragma unroll
        for (int i = 0; i < 4; ++i)
#pragma unroll
            for (int j = 0; j < 2; ++j)
                acc[i][j] = __builtin_amdgcn_mfma_f32_16x16x32_f16(av[i], bv[j], acc[i][j], 0, 0, 0);
        __syncthreads();
    }

#pragma unroll
    for (int i = 0; i < 4; ++i) {
        const int growb = rowA0 + wm + i * 16 + fq * 4;
#pragma unroll
        for (int j = 0; j < 2; ++j) {
            const int gcol = colB0 + wn + j * 16 + fm;
#pragma unroll
            for (int r = 0; r < 4; ++r) {
                float v = acc[i][j][r];
                size_t idx = (size_t)(growb + r) * N + gcol;
                if (OUT_HALF) Ch[idx] = (_Float16)v;
                else          Cf[idx] = v;
            }
        }
    }
}

// ---------------------------------------------------------------------------
// Workspace layout (104 MB used):
//  [0,32M)    P fp16 [4096][4096] (region reused: x_hi [0,8M), x_lo [8,16M),
//             wqkT_hi [16,20M), wqkT_lo [20,24M), wvT [24,26M) all dead
//             before the score kernel writes P)
//  [32,33M)   Marr fp32 [4096][64]   [33,34M) Larr fp32 [4096][64]
//  [34,34.5M) CarrT fp16 [64][4096]
//  [64,80M)   Qcat fp16 [4096][2048] (hi cols 0..1023, lo cols 1024..2047)
//  [80,96M)   Kcat fp16 [4096][2048]
//  [96,104M)  VT fp16 [1024][4096]
// ---------------------------------------------------------------------------
extern "C" void kernel_launch(void* const* d_in, const int* in_sizes, int n_in,
                              void* d_out, int out_size, void* d_ws, size_t ws_size,
                              hipStream_t stream) {
    const float* x  = (const float*)d_in[0];
    const float* wq = (const float*)d_in[1];
    const float* wk = (const float*)d_in[2];
    const float* wv = (const float*)d_in[3];
    float* out = (float*)d_out;

    char* base = (char*)d_ws;
    const size_t MB = 1u << 20;
    _Float16* P       = (_Float16*)base;               // [4096][4096]
    _Float16* x_hi    = (_Float16*)(base + 0 * MB);
    _Float16* x_lo    = (_Float16*)(base + 8 * MB);
    _Float16* wqkT_hi = (_Float16*)(base + 16 * MB);   // [2048][1024]
    _Float16* wqkT_lo = (_Float16*)(base + 20 * MB);
    _Float16* wvT     = (_Float16*)(base + 24 * MB);   // [1024][1024]
    float*    Marr    = (float*)(base + 32 * MB);
    float*    Larr    = (float*)(base + 33 * MB);
    _Float16* CarrT   = (_Float16*)(base + 34 * MB);   // [64][4096]
    _Float16* Qcat    = (_Float16*)(base + 64 * MB);   // [4096][2048]
    _Float16* Kcat    = (_Float16*)(base + 80 * MB);   // [4096][2048]
    _Float16* VT      = (_Float16*)(base + 96 * MB);   // [1024][4096]

    // 1) fused prep
    prep<<<4096, 256, 0, stream>>>(x, wq, wk, wv, x_hi, x_lo, wqkT_hi, wqkT_lo, wvT);

    // 2) QK projection, deep-pipelined merged-phase (exact 3-product)
    dim3 gqk(2048 / 256, SEQ / 128);   // (8,32) — XCD = col-panel
    gemm_qkproj_dp<<<gqk, dim3(512), 0, stream>>>(x_hi, x_lo, wqkT_hi, wqkT_lo,
                                                  Qcat, Kcat);
    // V^T = wv^T @ x^T, plain fp16, tile 128x64
    dim3 gvt(SEQ / 64, DMODEL / 128);  // (64,8)
    gemm_h16_n64<1><<<gvt, 256, 0, stream>>>(wvT, DMODEL, x_hi, DMODEL,
                                             nullptr, VT, SEQ, DMODEL);

    // 3) scores + tile-softmax, deep-pipelined 256x256 K=2048
    dim3 gs(SEQ / 256, SEQ / 256);     // (16,16)
    gemm_score_dp<<<gs, dim3(512), 0, stream>>>(Qcat, Kcat, P, Marr, Larr,
                                                1.0f / 32.0f);

    // 4) finalize coefficients only (no P traffic)
    compute_c<<<SEQ, 64, 0, stream>>>(Marr, Larr, CarrT);

    // 5) out = sum_t c_t * (P_t @ V_t), deep-pipelined merged-phase
    dim3 gpv(DMODEL / 128, SEQ / 128); // (8,32) — XCD = col-panel
    gemm_pv_dp<<<gpv, dim3(512), 0, stream>>>(P, VT, CarrT, out);
}

// Round 5
// 290.656 us; speedup vs baseline: 1.2142x; 1.0180x over previous
//
#include <hip/hip_runtime.h>
#include <hip/hip_fp16.h>
#include <math.h>

#define SEQ    4096
#define DMODEL 1024

typedef _Float16 half8   __attribute__((ext_vector_type(8)));
typedef _Float16 half4v  __attribute__((ext_vector_type(4)));
typedef float    floatx4 __attribute__((ext_vector_type(4)));

__device__ inline void split_val(float v, _Float16& h, _Float16& l) {
    _Float16 hh = (_Float16)v;
    h = hh;
    l = (_Float16)(v - (float)hh);
}

// ---------------------------------------------------------------------------
// Fused prep: blocks 0..3071 transpose wq/wk/wv (32x32 tiles); blocks
// 3072..4095 split x into hi/lo fp16 (4 float4 per thread = full x).
// ---------------------------------------------------------------------------
__global__ __launch_bounds__(256) void prep(const float* __restrict__ x,
                                            const float* __restrict__ wq,
                                            const float* __restrict__ wk,
                                            const float* __restrict__ wv,
                                            _Float16* __restrict__ x_hi,
                                            _Float16* __restrict__ x_lo,
                                            _Float16* __restrict__ wqkT_hi,
                                            _Float16* __restrict__ wqkT_lo,
                                            _Float16* __restrict__ wvT) {
    __shared__ float tile[32][33];
    const int b = blockIdx.x;
    if (b < 3072) {
        const int which = b >> 10;           // 0=wq 1=wk 2=wv
        const int bb = b & 1023;
        const int c0 = (bb & 31) * 32;
        const int r0 = (bb >> 5) * 32;
        const float* w = (which == 0) ? wq : (which == 1) ? wk : wv;
        const int tx = threadIdx.x & 31, ty = threadIdx.x >> 5;
#pragma unroll
        for (int j = 0; j < 4; ++j)
            tile[ty * 4 + j][tx] = w[(size_t)(r0 + ty * 4 + j) * DMODEL + c0 + tx];
        __syncthreads();
        if (which < 2) {
            _Float16* th = wqkT_hi + (size_t)which * DMODEL * DMODEL;
            _Float16* tl = wqkT_lo + (size_t)which * DMODEL * DMODEL;
#pragma unroll
            for (int j = 0; j < 4; ++j) {
                float v = tile[tx][ty * 4 + j];
                size_t idx = (size_t)(c0 + ty * 4 + j) * DMODEL + r0 + tx;
                _Float16 h, l;
                split_val(v, h, l);
                th[idx] = h;
                tl[idx] = l;
            }
        } else {
#pragma unroll
            for (int j = 0; j < 4; ++j)
                wvT[(size_t)(c0 + ty * 4 + j) * DMODEL + r0 + tx] =
                    (_Float16)tile[tx][ty * 4 + j];
        }
    } else {
        const int t0 = (b - 3072) * 256 + threadIdx.x;
#pragma unroll
        for (int rep = 0; rep < 4; ++rep) {
            const size_t i = (size_t)t0 + (size_t)rep * 262144;
            floatx4 v = *(const floatx4*)(x + 4 * i);
            half4v h, l;
#pragma unroll
            for (int j = 0; j < 4; ++j) {
                _Float16 hh = (_Float16)v[j];
                _Float16 ll = (_Float16)(v[j] - (float)hh);
                h[j] = hh;
                l[j] = ll;
            }
            *(half4v*)(x_hi + 4 * i) = h;
            *(half4v*)(x_lo + 4 * i) = l;
        }
    }
}

// ---------------------------------------------------------------------------
// QK projection, deep-pipelined, merged single phase per K-tile (unchanged
// from R4). Virtual K=3072: seg0 x_hi·w_hi, seg1 x_hi·w_lo, seg2 x_lo·w_hi
// (exact 3-product). Tile 128x256, BK=32, 8 waves (2Mx4N). 4-slot ring
// (96KB), 3 vmem/tile, gate vmcnt(6).
// ---------------------------------------------------------------------------
__global__ __launch_bounds__(512, 1) void gemm_qkproj_dp(
    const _Float16* __restrict__ Ahi, const _Float16* __restrict__ Alo,   // x_hi/x_lo [4096][1024]
    const _Float16* __restrict__ Bhi, const _Float16* __restrict__ Blo,   // wqkT_hi/lo [2048][1024]
    _Float16* __restrict__ Qcat, _Float16* __restrict__ Kcat) {
    __shared__ _Float16 As[4][128][32];   // 32 KB
    __shared__ _Float16 Bs[4][256][32];   // 64 KB

    const int tid  = threadIdx.x;
    const int lane = tid & 63;
    const int wid  = tid >> 6;
    const int wm   = (wid >> 2) * 64;     // 0,64
    const int wn   = (wid & 3) * 64;      // 0,64,128,192

    const int rowA0 = blockIdx.y * 128;
    const int colB0 = blockIdx.x * 256;

    // A staging: 512 granules (128 rows x 4), 1 per thread.
    const int ar  = tid >> 2;
    const int ag  = tid & 3;
    const int ags = ag ^ ((ar >> 1) & 3);
    const char* aHiB = (const char*)(Ahi + (size_t)(rowA0 + ar) * DMODEL) + ags * 16;
    const char* aLoB = (const char*)(Alo + (size_t)(rowA0 + ar) * DMODEL) + ags * 16;
    // B staging: 1024 granules (256 rows x 4), 2 per thread (rows r, r+128).
    const int br  = tid >> 2;
    const int bg  = tid & 3;
    const int bgs = bg ^ ((br >> 1) & 3);   // invariant under +128
    const char* bHi0 = (const char*)(Bhi + (size_t)(colB0 + br) * DMODEL) + bgs * 16;
    const char* bHi1 = (const char*)(Bhi + (size_t)(colB0 + br + 128) * DMODEL) + bgs * 16;
    const char* bLo0 = (const char*)(Blo + (size_t)(colB0 + br) * DMODEL) + bgs * 16;
    const char* bLo1 = (const char*)(Blo + (size_t)(colB0 + br + 128) * DMODEL) + bgs * 16;

#define STAGE_QA(tt)                                                                 \
    do {                                                                             \
        const int _s = (tt) & 3;                                                     \
        const char* _ab = ((tt) < 64) ? aHiB : aLoB;                                 \
        const size_t _ko = (size_t)((tt) & 31) * 64;                                 \
        __builtin_amdgcn_global_load_lds(                                            \
            (const __attribute__((address_space(1))) void*)(_ab + _ko),              \
            (__attribute__((address_space(3))) void*)&As[_s][ar][ag * 8], 16, 0, 0); \
    } while (0)

#define STAGE_QB(tt)                                                                 \
    do {                                                                             \
        const int _s = (tt) & 3;                                                     \
        const bool _lo = ((tt) >= 32) && ((tt) < 64);                                \
        const char* _b0 = _lo ? bLo0 : bHi0;                                         \
        const char* _b1 = _lo ? bLo1 : bHi1;                                         \
        const size_t _ko = (size_t)((tt) & 31) * 64;                                 \
        __builtin_amdgcn_global_load_lds(                                            \
            (const __attribute__((address_space(1))) void*)(_b0 + _ko),              \
            (__attribute__((address_space(3))) void*)&Bs[_s][br][bg * 8], 16, 0, 0); \
        __builtin_amdgcn_global_load_lds(                                            \
            (const __attribute__((address_space(1))) void*)(_b1 + _ko),              \
            (__attribute__((address_space(3))) void*)&Bs[_s][br + 128][bg * 8], 16, 0, 0);\
    } while (0)

    const int fm = lane & 15;
    const int fq = lane >> 4;
    const int ck = (fq ^ ((fm >> 1) & 3)) * 8;

    floatx4 acc[4][4] = {};

    auto tile_body = [&](int t, bool do_stage) {
        const int s = t & 3;
        half8 av[4], bv[4];
#pragma unroll
        for (int i = 0; i < 4; ++i) av[i] = *(const half8*)&As[s][wm + i * 16 + fm][ck];
#pragma unroll
        for (int j = 0; j < 4; ++j) bv[j] = *(const half8*)&Bs[s][wn + j * 16 + fm][ck];
        if (do_stage) { STAGE_QA(t + 3); STAGE_QB(t + 3); }
        asm volatile("" ::: "memory");
        __builtin_amdgcn_s_barrier();
        asm volatile("" ::: "memory");
        __builtin_amdgcn_s_setprio(1);
#pragma unroll
        for (int i = 0; i < 4; ++i)
#pragma unroll
            for (int j = 0; j < 4; ++j)
                acc[i][j] = __builtin_amdgcn_mfma_f32_16x16x32_f16(av[i], bv[j], acc[i][j], 0, 0, 0);
        __builtin_amdgcn_s_setprio(0);
    };

    // Prologue: stage tiles 0,1,2 (9 instrs); gate on tile 0 (6 outstanding).
    STAGE_QA(0); STAGE_QB(0);
    STAGE_QA(1); STAGE_QB(1);
    STAGE_QA(2); STAGE_QB(2);
    asm volatile("s_waitcnt vmcnt(6)" ::: "memory");
    __builtin_amdgcn_s_barrier();
    asm volatile("" ::: "memory");

    // 96 virtual K-tiles (3 segments x 32).
#pragma unroll 1
    for (int t = 0; t < 93; ++t) {
        tile_body(t, true);
        asm volatile("s_waitcnt vmcnt(6)" ::: "memory");
        __builtin_amdgcn_s_barrier();
        asm volatile("" ::: "memory");
    }
    tile_body(93, false);
    asm volatile("s_waitcnt vmcnt(3)" ::: "memory");
    __builtin_amdgcn_s_barrier();
    asm volatile("" ::: "memory");
    tile_body(94, false);
    asm volatile("s_waitcnt vmcnt(0)" ::: "memory");
    __builtin_amdgcn_s_barrier();
    asm volatile("" ::: "memory");
    tile_body(95, false);
#undef STAGE_QA
#undef STAGE_QB

    _Float16* dcat = Qcat;
    int cbase = colB0;
    if (colB0 >= 1024) { dcat = Kcat; cbase = colB0 - 1024; }

#pragma unroll
    for (int i = 0; i < 4; ++i) {
        const int growb = rowA0 + wm + i * 16 + fq * 4;
#pragma unroll
        for (int j = 0; j < 4; ++j) {
            const int gcol = wn + j * 16 + fm;
#pragma unroll
            for (int r = 0; r < 4; ++r) {
                float v = acc[i][j][r];
                size_t idx = (size_t)(growb + r) * 2048 + cbase + gcol;
                _Float16 h, l;
                split_val(v, h, l);
                dcat[idx] = h;
                dcat[idx + 1024] = l;
            }
        }
    }
}

// ---------------------------------------------------------------------------
// Score GEMM, deep-pipelined, NOW MERGED single phase per K-tile:
// {12 ds_read_b128 || STAGE A+B(t+3) || barrier || 32 MFMA (setprio) ||
//  gate vmcnt(8) || barrier}. Barriers/tile 4->2, one read-window instead
// of two — R4 measured 35% MfmaUtil with the 2-phase version; the merged
// window model predicts ~50%. Ring/vmcnt ledger identical to R4 (proven):
// STAGE(t+3) writes slot (t-1)&3 whose ds_reads completed (lgkm before
// tile t-1's MFMA) ahead of the end-barrier of t-1; gate vmcnt(8) at end
// of tile t = tiles t+2,t+3 (8 loads) in flight, t+1 landed.
// S = Qcat @ Kcat^T (fp16, K=2048), tile 256x256, BK=32, 8 waves.
// Tile-softmax epilogue unchanged.
// ---------------------------------------------------------------------------
__global__ __launch_bounds__(512, 2) void gemm_score_dp(
    const _Float16* __restrict__ Qc,   // [4096][2048]
    const _Float16* __restrict__ Kc,   // [4096][2048]
    _Float16* __restrict__ Ph, float* __restrict__ Marr, float* __restrict__ Larr,
    float scale) {
    __shared__ _Float16 As[4][256][32];   // 64 KB
    __shared__ _Float16 Bs[4][256][32];   // 64 KB

    const int tid  = threadIdx.x;
    const int lane = tid & 63;
    const int wid  = tid >> 6;
    const int wm   = (wid >> 2) * 128;    // 0 or 128
    const int wn   = (wid & 3) * 64;      // 0,64,128,192

    // XCD-aware bijective swizzle: nwg = 256 (grid 16 x 16).
    const int lin = blockIdx.y * 16 + blockIdx.x;
    const int swz = (lin & 7) * 32 + (lin >> 3);
    const int rowA0 = (swz >> 4) * 256;
    const int colB0 = (swz & 15) * 256;

    const int pr  = tid >> 2;
    const int pg  = tid & 3;
    const int pgs = pg ^ ((pr >> 1) & 3);

    const char* aSrc0 = (const char*)(Qc + (size_t)(rowA0 + pr) * 2048) + pgs * 16;
    const char* aSrc1 = (const char*)(Qc + (size_t)(rowA0 + pr + 128) * 2048) + pgs * 16;
    const char* bSrc0 = (const char*)(Kc + (size_t)(colB0 + pr) * 2048) + pgs * 16;
    const char* bSrc1 = (const char*)(Kc + (size_t)(colB0 + pr + 128) * 2048) + pgs * 16;

#define STAGE_A(t)                                                                  \
    do {                                                                            \
        const int _s = (t) & 3;                                                     \
        const size_t _ko = (size_t)(t) * 64;                                        \
        __builtin_amdgcn_global_load_lds(                                           \
            (const __attribute__((address_space(1))) void*)(aSrc0 + _ko),           \
            (__attribute__((address_space(3))) void*)&As[_s][pr][pg * 8], 16, 0, 0);\
        __builtin_amdgcn_global_load_lds(                                           \
            (const __attribute__((address_space(1))) void*)(aSrc1 + _ko),           \
            (__attribute__((address_space(3))) void*)&As[_s][pr + 128][pg * 8], 16, 0, 0);\
    } while (0)

#define STAGE_B(t)                                                                  \
    do {                                                                            \
        const int _s = (t) & 3;                                                     \
        const size_t _ko = (size_t)(t) * 64;                                        \
        __builtin_amdgcn_global_load_lds(                                           \
            (const __attribute__((address_space(1))) void*)(bSrc0 + _ko),           \
            (__attribute__((address_space(3))) void*)&Bs[_s][pr][pg * 8], 16, 0, 0);\
        __builtin_amdgcn_global_load_lds(                                           \
            (const __attribute__((address_space(1))) void*)(bSrc1 + _ko),           \
            (__attribute__((address_space(3))) void*)&Bs[_s][pr + 128][pg * 8], 16, 0, 0);\
    } while (0)

    const int fm = lane & 15;
    const int fq = lane >> 4;
    const int ck = (fq ^ ((fm >> 1) & 3)) * 8;

    floatx4 acc[8][4] = {};

    auto tile_body = [&](int t, bool do_stage) {
        const int s = t & 3;
        half8 av[4], av2[4], bv[4];
#pragma unroll
        for (int i = 0; i < 4; ++i) av[i]  = *(const half8*)&As[s][wm + i * 16 + fm][ck];
#pragma unroll
        for (int i = 0; i < 4; ++i) av2[i] = *(const half8*)&As[s][wm + 64 + i * 16 + fm][ck];
#pragma unroll
        for (int j = 0; j < 4; ++j) bv[j]  = *(const half8*)&Bs[s][wn + j * 16 + fm][ck];
        if (do_stage) { STAGE_A(t + 3); STAGE_B(t + 3); }
        asm volatile("" ::: "memory");
        __builtin_amdgcn_s_barrier();
        asm volatile("" ::: "memory");
        __builtin_amdgcn_s_setprio(1);
#pragma unroll
        for (int i = 0; i < 4; ++i)
#pragma unroll
            for (int j = 0; j < 4; ++j)
                acc[i][j] = __builtin_amdgcn_mfma_f32_16x16x32_f16(av[i], bv[j], acc[i][j], 0, 0, 0);
#pragma unroll
        for (int i = 0; i < 4; ++i)
#pragma unroll
            for (int j = 0; j < 4; ++j)
                acc[i + 4][j] = __builtin_amdgcn_mfma_f32_16x16x32_f16(av2[i], bv[j], acc[i + 4][j], 0, 0, 0);
        __builtin_amdgcn_s_setprio(0);
    };

    STAGE_A(0); STAGE_B(0);
    STAGE_A(1); STAGE_B(1);
    STAGE_A(2); STAGE_B(2);
    asm volatile("s_waitcnt vmcnt(8)" ::: "memory");
    __builtin_amdgcn_s_barrier();
    asm volatile("" ::: "memory");

#pragma unroll 1
    for (int t = 0; t < 61; ++t) {
        tile_body(t, true);
        asm volatile("s_waitcnt vmcnt(8)" ::: "memory");
        __builtin_amdgcn_s_barrier();
        asm volatile("" ::: "memory");
    }
    tile_body(61, false);
    asm volatile("s_waitcnt vmcnt(4)" ::: "memory");
    __builtin_amdgcn_s_barrier();
    asm volatile("" ::: "memory");
    tile_body(62, false);
    asm volatile("s_waitcnt vmcnt(0)" ::: "memory");
    __builtin_amdgcn_s_barrier();
    asm volatile("" ::: "memory");
    tile_body(63, false);
#undef STAGE_A
#undef STAGE_B

    const int tprime = (colB0 + wn) >> 6;
#pragma unroll
    for (int i = 0; i < 8; ++i) {
#pragma unroll
        for (int r = 0; r < 4; ++r) {
            const int grow = rowA0 + wm + i * 16 + fq * 4 + r;
            float s0 = acc[i][0][r] * scale;
            float s1 = acc[i][1][r] * scale;
            float s2 = acc[i][2][r] * scale;
            float s3 = acc[i][3][r] * scale;
            float mx = fmaxf(fmaxf(s0, s1), fmaxf(s2, s3));
            mx = fmaxf(mx, __shfl_xor(mx, 1));
            mx = fmaxf(mx, __shfl_xor(mx, 2));
            mx = fmaxf(mx, __shfl_xor(mx, 4));
            mx = fmaxf(mx, __shfl_xor(mx, 8));
            float p0 = __expf(s0 - mx);
            float p1 = __expf(s1 - mx);
            float p2 = __expf(s2 - mx);
            float p3 = __expf(s3 - mx);
            float sum = p0 + p1 + p2 + p3;
            sum += __shfl_xor(sum, 1);
            sum += __shfl_xor(sum, 2);
            sum += __shfl_xor(sum, 4);
            sum += __shfl_xor(sum, 8);
            _Float16* prow = Ph + (size_t)grow * SEQ + colB0 + wn + fm;
            prow[0]  = (_Float16)p0;
            prow[16] = (_Float16)p1;
            prow[32] = (_Float16)p2;
            prow[48] = (_Float16)p3;
            if (fm == 0) {
                Marr[(size_t)grow * 64 + tprime] = mx;
                Larr[(size_t)grow * 64 + tprime] = sum;
            }
        }
    }
}

// ---------------------------------------------------------------------------
// compute_c, coalesced: 64 rows per block (grid 64, 256 threads = 4 waves).
// Wave w handles rows w*16..w*16+15 (its 64 lanes = the 64 t-values),
// computes c into LDS, then each wave writes 16 CarrT rows as contiguous
// 128B spans. Replaces the 2-byte-scatter writer (64 scattered stores/block
// x 4096 blocks).
// ---------------------------------------------------------------------------
__global__ __launch_bounds__(256) void compute_c(const float* __restrict__ Marr,
                                                 const float* __restrict__ Larr,
                                                 _Float16* __restrict__ CarrT) {
    __shared__ float c_s[64][65];
    const int row0 = blockIdx.x * 64;
    const int wv = threadIdx.x >> 6;
    const int ln = threadIdx.x & 63;

#pragma unroll
    for (int k = 0; k < 16; ++k) {
        const int r = wv * 16 + k;
        float mt = Marr[(size_t)(row0 + r) * 64 + ln];
        float lt = Larr[(size_t)(row0 + r) * 64 + ln];
        float m = mt;
#pragma unroll
        for (int off = 32; off > 0; off >>= 1) m = fmaxf(m, __shfl_xor(m, off));
        float e = __expf(mt - m);
        float L = lt * e;
#pragma unroll
        for (int off = 32; off > 0; off >>= 1) L += __shfl_xor(L, off);
        c_s[r][ln] = e / L;
    }
    __syncthreads();

#pragma unroll
    for (int k = 0; k < 16; ++k) {
        const int t = wv * 16 + k;
        CarrT[(size_t)t * SEQ + row0 + ln] = (_Float16)c_s[ln][t];
    }
}

// ---------------------------------------------------------------------------
// PV GEMM, deep-pipelined merged phase (unchanged from R4): out =
// sum_t c[row][t] * (P_t @ V_t), tile 128x128, BK=64, 4-slot ring (128KB)
// + cT 16KB, gate vmcnt(8).
// ---------------------------------------------------------------------------
__global__ __launch_bounds__(512, 1) void gemm_pv_dp(
    const _Float16* __restrict__ P,      // [4096][4096] (unscaled exp)
    const _Float16* __restrict__ VT,     // [1024][4096]
    const _Float16* __restrict__ CarrT,  // [64][4096]
    float* __restrict__ out) {           // [4096][1024]
    __shared__ _Float16 As[4][128][64];   // 64 KB
    __shared__ _Float16 Bs[4][128][64];   // 64 KB
    __shared__ _Float16 cT[64][128];      // 16 KB

    const int tid  = threadIdx.x;
    const int lane = tid & 63;
    const int wid  = tid >> 6;
    const int wm   = (wid >> 2) * 64;     // 0,64
    const int wn   = (wid & 3) * 32;      // 0,32,64,96

    const int rowA0 = blockIdx.y * 128;
    const int colB0 = blockIdx.x * 128;

    // Preload this block's c slab: cT[t][r] = CarrT[t][rowA0+r].
    {
        int g = tid;
#pragma unroll
        for (int it = 0; it < 2; ++it, g += 512) {
            const int t  = g >> 4;
            const int r8 = (g & 15) * 8;
            *(half8*)&cT[t][r8] =
                *(const half8*)(CarrT + (size_t)t * SEQ + rowA0 + r8);
        }
    }
    __syncthreads();

    const int prow = tid >> 3;            // 0..63
    const int pgr  = tid & 7;
    const int ags  = pgr ^ (prow & 7);
    const char* aSrc0 = (const char*)(P  + (size_t)(rowA0 + prow) * SEQ) + ags * 16;
    const char* aSrc1 = (const char*)(P  + (size_t)(rowA0 + prow + 64) * SEQ) + ags * 16;
    const char* bSrc0 = (const char*)(VT + (size_t)(colB0 + prow) * SEQ) + ags * 16;
    const char* bSrc1 = (const char*)(VT + (size_t)(colB0 + prow + 64) * SEQ) + ags * 16;

#define STAGE_PA(tt)                                                                \
    do {                                                                            \
        const int _s = (tt) & 3;                                                    \
        const size_t _ko = (size_t)(tt) * 128;                                      \
        __builtin_amdgcn_global_load_lds(                                           \
            (const __attribute__((address_space(1))) void*)(aSrc0 + _ko),           \
            (__attribute__((address_space(3))) void*)&As[_s][prow][pgr * 8], 16, 0, 0);\
        __builtin_amdgcn_global_load_lds(                                           \
            (const __attribute__((address_space(1))) void*)(aSrc1 + _ko),           \
            (__attribute__((address_space(3))) void*)&As[_s][prow + 64][pgr * 8], 16, 0, 0);\
    } while (0)

#define STAGE_PB(tt)                                                                \
    do {                                                                            \
        const int _s = (tt) & 3;                                                    \
        const size_t _ko = (size_t)(tt) * 128;                                      \
        __builtin_amdgcn_global_load_lds(                                           \
            (const __attribute__((address_space(1))) void*)(bSrc0 + _ko),           \
            (__attribute__((address_space(3))) void*)&Bs[_s][prow][pgr * 8], 16, 0, 0);\
        __builtin_amdgcn_global_load_lds(                                           \
            (const __attribute__((address_space(1))) void*)(bSrc1 + _ko),           \
            (__attribute__((address_space(3))) void*)&Bs[_s][prow + 64][pgr * 8], 16, 0, 0);\
    } while (0)

    const int fm = lane & 15;
    const int fq = lane >> 4;
    const int ck0 = ((fq    ) ^ (fm & 7)) * 8;   // k-slice 0 (k0..k0+31)
    const int ck1 = ((fq + 4) ^ (fm & 7)) * 8;   // k-slice 1 (k0+32..k0+63)

    floatx4 acc[4][2] = {};

    auto tile_body = [&](int t, bool do_stage) {
        const int s = t & 3;
        half8 av[4], av2[4], bv[2], bv2[2];
        _Float16 cs[4];
#pragma unroll
        for (int i = 0; i < 4; ++i) {
            av[i]  = *(const half8*)&As[s][wm + i * 16 + fm][ck0];
            av2[i] = *(const half8*)&As[s][wm + i * 16 + fm][ck1];
            cs[i]  = cT[t][wm + i * 16 + fm];
        }
#pragma unroll
        for (int j = 0; j < 2; ++j) {
            bv[j]  = *(const half8*)&Bs[s][wn + j * 16 + fm][ck0];
            bv2[j] = *(const half8*)&Bs[s][wn + j * 16 + fm][ck1];
        }
#pragma unroll
        for (int i = 0; i < 4; ++i)
#pragma unroll
            for (int e = 0; e < 8; ++e) {
                av[i][e]  *= cs[i];
                av2[i][e] *= cs[i];
            }
        if (do_stage) { STAGE_PA(t + 3); STAGE_PB(t + 3); }
        asm volatile("" ::: "memory");
        __builtin_amdgcn_s_barrier();
        asm volatile("" ::: "memory");
        __builtin_amdgcn_s_setprio(1);
#pragma unroll
        for (int i = 0; i < 4; ++i)
#pragma unroll
            for (int j = 0; j < 2; ++j)
                acc[i][j] = __builtin_amdgcn_mfma_f32_16x16x32_f16(av[i], bv[j], acc[i][j], 0, 0, 0);
#pragma unroll
        for (int i = 0; i < 4; ++i)
#pragma unroll
            for (int j = 0; j < 2; ++j)
                acc[i][j] = __builtin_amdgcn_mfma_f32_16x16x32_f16(av2[i], bv2[j], acc[i][j], 0, 0, 0);
        __builtin_amdgcn_s_setprio(0);
    };

    STAGE_PA(0); STAGE_PB(0);
    STAGE_PA(1); STAGE_PB(1);
    STAGE_PA(2); STAGE_PB(2);
    asm volatile("s_waitcnt vmcnt(8)" ::: "memory");
    __builtin_amdgcn_s_barrier();
    asm volatile("" ::: "memory");

    // 64 K-tiles (K = 4096, BK = 64).
#pragma unroll 1
    for (int t = 0; t < 61; ++t) {
        tile_body(t, true);
        asm volatile("s_waitcnt vmcnt(8)" ::: "memory");
        __builtin_amdgcn_s_barrier();
        asm volatile("" ::: "memory");
    }
    tile_body(61, false);
    asm volatile("s_waitcnt vmcnt(4)" ::: "memory");
    __builtin_amdgcn_s_barrier();
    asm volatile("" ::: "memory");
    tile_body(62, false);
    asm volatile("s_waitcnt vmcnt(0)" ::: "memory");
    __builtin_amdgcn_s_barrier();
    asm volatile("" ::: "memory");
    tile_body(63, false);
#undef STAGE_PA
#undef STAGE_PB

#pragma unroll
    for (int i = 0; i < 4; ++i) {
        const int growb = rowA0 + wm + i * 16 + fq * 4;
#pragma unroll
        for (int j = 0; j < 2; ++j) {
            const int gcol = colB0 + wn + j * 16 + fm;
#pragma unroll
            for (int r = 0; r < 4; ++r)
                out[(size_t)(growb + r) * DMODEL + gcol] = acc[i][j][r];
        }
    }
}

// ---------------------------------------------------------------------------
// Plain fp16 MFMA GEMM, tile 128x64 (16x16x32): V-projection.
// ---------------------------------------------------------------------------
template <int OUT_HALF>
__global__ __launch_bounds__(256) void gemm_h16_n64(
    const _Float16* __restrict__ A, int lda,
    const _Float16* __restrict__ B, int ldb,
    float* __restrict__ Cf, _Float16* __restrict__ Ch,
    int N, int K) {
    __shared__ _Float16 Ah[128][32];
    __shared__ _Float16 Bh[64][32];

    const int tid = threadIdx.x;
    const int lane = tid & 63;
    const int w = tid >> 6;
    const int wm = (w >> 1) * 64;
    const int wn = (w & 1) * 32;

    const int rowA0 = blockIdx.y * 128;
    const int colB0 = blockIdx.x * 64;

    const int sr = lane >> 2;
    const int sc = lane & 3;
    const int ra0 = w * 32 + sr;
    const int ra1 = ra0 + 16;
    const int rb0 = w * 16 + sr;
    const int cga0 = sc ^ ((ra0 >> 1) & 3);
    const int cga1 = sc ^ ((ra1 >> 1) & 3);
    const int cgb0 = sc ^ ((rb0 >> 1) & 3);

    const char* gp[3];
    gp[0] = (const char*)(A + (size_t)(rowA0 + ra0) * lda) + cga0 * 16;
    gp[1] = (const char*)(A + (size_t)(rowA0 + ra1) * lda) + cga1 * 16;
    gp[2] = (const char*)(B + (size_t)(colB0 + rb0) * ldb) + cgb0 * 16;

    _Float16* lp[3] = {
        &Ah[w * 32][0], &Ah[w * 32 + 16][0],
        &Bh[w * 16][0],
    };

    const int fm = lane & 15;
    const int fq = lane >> 4;
    const int ck = ((fq ^ ((fm >> 1) & 3)) * 8);

    floatx4 acc[4][2] = {};

    for (int k0 = 0; k0 < K; k0 += 32) {
#pragma unroll
        for (int t = 0; t < 3; ++t)
            __builtin_amdgcn_global_load_lds(
                (const __attribute__((address_space(1))) void*)gp[t],
                (__attribute__((address_space(3))) void*)lp[t], 16, 0, 0);
#pragma unroll
        for (int t = 0; t < 3; ++t) gp[t] += 64;
        __syncthreads();

        half8 av[4], bv[2];
#pragma unroll
        for (int i = 0; i < 4; ++i)
            av[i] = *(const half8*)&Ah[wm + i * 16 + fm][ck];
#pragma unroll
        for (int j = 0; j < 2; ++j)
            bv[j] = *(const half8*)&Bh[wn + j * 16 + fm][ck];
#pragma unroll
        for (int i = 0; i < 4; ++i)
#pragma unroll
            for (int j = 0; j < 2; ++j)
                acc[i][j] = __builtin_amdgcn_mfma_f32_16x16x32_f16(av[i], bv[j], acc[i][j], 0, 0, 0);
        __syncthreads();
    }

#pragma unroll
    for (int i = 0; i < 4; ++i) {
        const int growb = rowA0 + wm + i * 16 + fq * 4;
#pragma unroll
        for (int j = 0; j < 2; ++j) {
            const int gcol = colB0 + wn + j * 16 + fm;
#pragma unroll
            for (int r = 0; r < 4; ++r) {
                float v = acc[i][j][r];
                size_t idx = (size_t)(growb + r) * N + gcol;
                if (OUT_HALF) Ch[idx] = (_Float16)v;
                else          Cf[idx] = v;
            }
        }
    }
}

// ---------------------------------------------------------------------------
// Workspace layout (104 MB used):
//  [0,32M)    P fp16 [4096][4096] (region reused: x_hi [0,8M), x_lo [8,16M),
//             wqkT_hi [16,20M), wqkT_lo [20,24M), wvT [24,26M) all dead
//             before the score kernel writes P)
//  [32,33M)   Marr fp32 [4096][64]   [33,34M) Larr fp32 [4096][64]
//  [34,34.5M) CarrT fp16 [64][4096]
//  [64,80M)   Qcat fp16 [4096][2048] (hi cols 0..1023, lo cols 1024..2047)
//  [80,96M)   Kcat fp16 [4096][2048]
//  [96,104M)  VT fp16 [1024][4096]
// ---------------------------------------------------------------------------
extern "C" void kernel_launch(void* const* d_in, const int* in_sizes, int n_in,
                              void* d_out, int out_size, void* d_ws, size_t ws_size,
                              hipStream_t stream) {
    const float* x  = (const float*)d_in[0];
    const float* wq = (const float*)d_in[1];
    const float* wk = (const float*)d_in[2];
    const float* wv = (const float*)d_in[3];
    float* out = (float*)d_out;

    char* base = (char*)d_ws;
    const size_t MB = 1u << 20;
    _Float16* P       = (_Float16*)base;               // [4096][4096]
    _Float16* x_hi    = (_Float16*)(base + 0 * MB);
    _Float16* x_lo    = (_Float16*)(base + 8 * MB);
    _Float16* wqkT_hi = (_Float16*)(base + 16 * MB);   // [2048][1024]
    _Float16* wqkT_lo = (_Float16*)(base + 20 * MB);
    _Float16* wvT     = (_Float16*)(base + 24 * MB);   // [1024][1024]
    float*    Marr    = (float*)(base + 32 * MB);
    float*    Larr    = (float*)(base + 33 * MB);
    _Float16* CarrT   = (_Float16*)(base + 34 * MB);   // [64][4096]
    _Float16* Qcat    = (_Float16*)(base + 64 * MB);   // [4096][2048]
    _Float16* Kcat    = (_Float16*)(base + 80 * MB);   // [4096][2048]
    _Float16* VT      = (_Float16*)(base + 96 * MB);   // [1024][4096]

    // 1) fused prep
    prep<<<4096, 256, 0, stream>>>(x, wq, wk, wv, x_hi, x_lo, wqkT_hi, wqkT_lo, wvT);

    // 2) QK projection, deep-pipelined merged-phase (exact 3-product)
    dim3 gqk(2048 / 256, SEQ / 128);   // (8,32) — XCD = col-panel
    gemm_qkproj_dp<<<gqk, dim3(512), 0, stream>>>(x_hi, x_lo, wqkT_hi, wqkT_lo,
                                                  Qcat, Kcat);
    // V^T = wv^T @ x^T, plain fp16, tile 128x64
    dim3 gvt(SEQ / 64, DMODEL / 128);  // (64,8)
    gemm_h16_n64<1><<<gvt, 256, 0, stream>>>(wvT, DMODEL, x_hi, DMODEL,
                                             nullptr, VT, SEQ, DMODEL);

    // 3) scores + tile-softmax, deep-pipelined single-phase 256x256 K=2048
    dim3 gs(SEQ / 256, SEQ / 256);     // (16,16)
    gemm_score_dp<<<gs, dim3(512), 0, stream>>>(Qcat, Kcat, P, Marr, Larr,
                                                1.0f / 32.0f);

    // 4) finalize coefficients only (no P traffic), coalesced writes
    compute_c<<<SEQ / 64, 256, 0, stream>>>(Marr, Larr, CarrT);

    // 5) out = sum_t c_t * (P_t @ V_t), deep-pipelined merged-phase
    dim3 gpv(DMODEL / 128, SEQ / 128); // (8,32) — XCD = col-panel
    gemm_pv_dp<<<gpv, dim3(512), 0, stream>>>(P, VT, CarrT, out);
}